// Round 1
// baseline (614.414 us; speedup 1.0000x reference)
//
#include <hip/hip_runtime.h>
#include <math.h>

#define N_PIX 2304
#define CCH   256
#define NHEAD 8
#define DHEAD 32
#define BHN   16     // B * NHEAD
#define KTOP  576
#define NROWS 4608   // B * N_PIX

// ======================= LayerNorm (over C=256) =======================
// in layout: offset = b*C*N + n*rowStride + c*elemStride
// NCHW: rowStride=1, elemStride=N ; NHWC: rowStride=C, elemStride=1
__global__ __launch_bounds__(256) void ln_kernel(
    const float* __restrict__ in, float* __restrict__ out,
    const float* __restrict__ g, const float* __restrict__ bvec,
    int elemStride, int rowStride)
{
  int r = blockIdx.x;                 // 0..4607  (b,n)
  int b = r / N_PIX, n = r - b * N_PIX;
  const float* p = in + (long)b * CCH * N_PIX + (long)n * rowStride;
  int c = threadIdx.x;
  float v = p[(long)c * elemStride];
  __shared__ float red[256];
  red[c] = v; __syncthreads();
  for (int off = 128; off > 0; off >>= 1) { if (c < off) red[c] += red[c + off]; __syncthreads(); }
  float mu = red[0] * (1.f / 256.f);
  __syncthreads();
  float dv = v - mu;
  red[c] = dv * dv; __syncthreads();
  for (int off = 128; off > 0; off >>= 1) { if (c < off) red[c] += red[c + off]; __syncthreads(); }
  float var = red[0] * (1.f / 256.f);
  out[(long)r * CCH + c] = dv * rsqrtf(var + 1e-6f) * g[c] + bvec[c];
}

// ======================= Generic fp32 GEMM 64x64x16 =======================
// C[M,N] = A[M,K] @ B[K,N], row-major. batch via blockIdx.z with strides.
// EPI: 0 = (+bias)(+add) ; 1 = gelu(acc+bias) ; 2 = silu(acc+bias) ;
//      3 = final FFN: out_nchw = add_nhwc + gamma*(acc+bias), N must be 256.
template<int EPI>
__global__ __launch_bounds__(256) void gemm_kernel(
    const float* __restrict__ A, const float* __restrict__ B, float* __restrict__ C,
    int M, int N, int K,
    const float* __restrict__ bias, const float* __restrict__ add,
    const float* __restrict__ gamma,
    long sA, long sB, long sC)
{
  __shared__ float As[16][68];  // As[k][m]
  __shared__ float Bs[16][68];  // Bs[k][n]
  int bz = blockIdx.z;
  A += sA * bz; B += sB * bz; C += sC * bz;
  int tid = threadIdx.x;
  int tx = tid & 15, ty = tid >> 4;
  int row0 = blockIdx.y * 64, col0 = blockIdx.x * 64;
  int ar = tid >> 2, ac = (tid & 3) << 2;      // A-tile load coords
  int br = tid >> 4, bc = (tid & 15) << 2;     // B-tile load coords
  float acc[4][4] = {{0.f}};
  const float* Aptr = A + (long)(row0 + ar) * K + ac;
  const float* Bptr = B + (long)br * N + col0 + bc;
  bool bvalid = (col0 + bc) < N;               // all N are multiples of 4
  for (int k0 = 0; k0 < K; k0 += 16) {
    float4 av = *(const float4*)(Aptr);
    Aptr += 16;
    float4 bv = make_float4(0.f, 0.f, 0.f, 0.f);
    if (bvalid) bv = *(const float4*)(Bptr);
    Bptr += (long)16 * N;
    As[ac + 0][ar] = av.x; As[ac + 1][ar] = av.y; As[ac + 2][ar] = av.z; As[ac + 3][ar] = av.w;
    *(float4*)&Bs[br][bc] = bv;
    __syncthreads();
#pragma unroll
    for (int kk = 0; kk < 16; ++kk) {
      float4 a = *(const float4*)&As[kk][ty << 2];
      float4 b = *(const float4*)&Bs[kk][tx << 2];
      acc[0][0] += a.x * b.x; acc[0][1] += a.x * b.y; acc[0][2] += a.x * b.z; acc[0][3] += a.x * b.w;
      acc[1][0] += a.y * b.x; acc[1][1] += a.y * b.y; acc[1][2] += a.y * b.z; acc[1][3] += a.y * b.w;
      acc[2][0] += a.z * b.x; acc[2][1] += a.z * b.y; acc[2][2] += a.z * b.z; acc[2][3] += a.z * b.w;
      acc[3][0] += a.w * b.x; acc[3][1] += a.w * b.y; acc[3][2] += a.w * b.z; acc[3][3] += a.w * b.w;
    }
    __syncthreads();
  }
  if (EPI == 3) {
    // final: C (d_out, NCHW) = add(x2, NHWC) + gamma*(acc + bias)
    int r0 = row0 + (ty << 2);
    int bb = r0 / N_PIX; int p = r0 - bb * N_PIX;
    float g2 = gamma[0];
#pragma unroll
    for (int j = 0; j < 4; ++j) {
      int c = col0 + (tx << 2) + j;
      float4 res;
      res.x = add[(long)(r0 + 0) * 256 + c] + g2 * (acc[0][j] + bias[c]);
      res.y = add[(long)(r0 + 1) * 256 + c] + g2 * (acc[1][j] + bias[c]);
      res.z = add[(long)(r0 + 2) * 256 + c] + g2 * (acc[2][j] + bias[c]);
      res.w = add[(long)(r0 + 3) * 256 + c] + g2 * (acc[3][j] + bias[c]);
      *(float4*)&C[((long)bb * 256 + c) * N_PIX + p] = res;
    }
  } else {
#pragma unroll
    for (int i = 0; i < 4; ++i) {
      long r = row0 + (ty << 2) + i;
#pragma unroll
      for (int j = 0; j < 4; ++j) {
        int c = col0 + (tx << 2) + j;
        if (c >= N) continue;
        float v = acc[i][j];
        if (bias) v += bias[c];
        if (EPI == 1) v = 0.5f * v * (1.f + erff(v * 0.70710678118654752f));
        if (EPI == 2) v = v / (1.f + expf(-v));
        if (EPI == 0 && add) v += add[r * N + c];
        C[r * N + c] = v;
      }
    }
  }
}

// ======================= q/k/v sums per (b,h) =======================
// acc layout: [bh][96] : 0..31 q_sum, 32..63 k_sum, 64..95 v_sum
__global__ __launch_bounds__(128) void qkv_sums_kernel(
    const float* __restrict__ qkv, float* __restrict__ acc)
{
  int bh = blockIdx.x, chunk = blockIdx.y;
  int j = threadIdx.x;
  if (j >= 96) return;
  int b = bh >> 3, h = bh & 7;
  int col = (j >> 5) * 256 + h * 32 + (j & 31);
  int n0 = chunk * 144;
  const float* p = qkv + ((long)(b * N_PIX + n0)) * 768 + col;
  float s = 0.f;
  for (int t = 0; t < 144; ++t) { s += *p; p += 768; }
  atomicAdd(&acc[bh * 96 + j], s);
}

// ======================= rank-1 row/col scores =======================
__global__ __launch_bounds__(256) void score_kernel(
    const float* __restrict__ qkv, const float* __restrict__ acc,
    float* __restrict__ rs, float* __restrict__ cs)
{
  int idx = blockIdx.x * 256 + threadIdx.x;     // 16*2304
  if (idx >= BHN * N_PIX) return;
  int bh = idx / N_PIX, n = idx - bh * N_PIX;
  int b = bh >> 3, h = bh & 7;
  const float* qp = qkv + ((long)(b * N_PIX + n)) * 768 + h * 32;
  const float* qs = acc + bh * 96;
  const float* ks = acc + bh * 96 + 32;
  float r = 0.f, c = 0.f;
#pragma unroll
  for (int d = 0; d < 32; ++d) { r += qp[d] * ks[d]; c += qp[256 + d] * qs[d]; }
  rs[idx] = r; cs[idx] = c;
}

// ======================= exact top-576 (radix select, jax tie rule) ===
__device__ __forceinline__ unsigned int excl_scan256(unsigned int val, unsigned int* tmp, int tid) {
  tmp[tid] = val; __syncthreads();
#pragma unroll
  for (int off = 1; off < 256; off <<= 1) {
    unsigned int t = (tid >= off) ? tmp[tid - off] : 0u;
    __syncthreads();
    tmp[tid] += t;
    __syncthreads();
  }
  unsigned int incl = tmp[tid];
  __syncthreads();
  return incl - val;
}

__global__ __launch_bounds__(256) void topk_kernel(
    const float* __restrict__ scores, int* __restrict__ out_idx)
{
  int bh = blockIdx.x;
  int which = blockIdx.y;  // 0 rows, 1 cols
  const float* s = scores + (long)(which * BHN + bh) * N_PIX;
  int* out = out_idx + (which * BHN + bh) * KTOP;
  __shared__ unsigned int u[N_PIX];
  __shared__ unsigned int hist[256];
  __shared__ unsigned int tmp[256];
  __shared__ unsigned int bc0, bc1;
  __shared__ unsigned int run_sel, run_eq;
  int tid = threadIdx.x;
  for (int i = tid; i < N_PIX; i += 256) {
    unsigned int b = __float_as_uint(s[i]);
    u[i] = (b & 0x80000000u) ? ~b : (b | 0x80000000u);  // order-preserving map
  }
  __syncthreads();
  unsigned int prefix = 0u, kRem = KTOP;
  for (int pass = 0; pass < 4; ++pass) {
    int shift = 24 - pass * 8;
    hist[tid] = 0u;
    __syncthreads();
    unsigned int mask = (pass == 0) ? 0u : (0xFFFFFFFFu << (shift + 8));
    for (int i = tid; i < N_PIX; i += 256) {
      unsigned int v = u[i];
      if ((v & mask) == prefix) atomicAdd(&hist[(v >> shift) & 255u], 1u);
    }
    __syncthreads();
    if (tid == 0) {
      unsigned int cum = 0u, sel = 0u;
      for (int bv = 255; bv >= 0; --bv) {
        unsigned int cb = hist[bv];
        if (cum + cb >= kRem) { sel = (unsigned int)bv; break; }
        cum += cb;
      }
      bc0 = sel; bc1 = cum;
    }
    __syncthreads();
    prefix |= (bc0 << shift);
    kRem -= bc1;
    __syncthreads();
  }
  unsigned int T = prefix;   // exact u-value of the 576th largest
  if (tid == 0) { run_sel = 0u; run_eq = 0u; }
  __syncthreads();
  for (int c0 = 0; c0 < N_PIX; c0 += 256) {
    int i = c0 + tid;
    unsigned int v = u[i];
    unsigned int isGt = (v > T) ? 1u : 0u;
    unsigned int isEq = (v == T) ? 1u : 0u;
    unsigned int eqPre = excl_scan256(isEq, tmp, tid);
    unsigned int eqRank = run_eq + eqPre;
    unsigned int selF = (isGt || (isEq && eqRank < kRem)) ? 1u : 0u;
    unsigned int selPre = excl_scan256(selF, tmp, tid);
    unsigned int pos = run_sel + selPre;
    if (selF && pos < KTOP) out[pos] = i;
    __syncthreads();
    if (tid == 255) { run_sel += selPre + selF; run_eq += eqPre + isEq; }
    __syncthreads();
  }
}

// ======================= gather kept rows/cols =======================
__global__ __launch_bounds__(256) void gather_kernel(
    const float* __restrict__ qkv, const int* __restrict__ idx,
    float* __restrict__ Qg, float* __restrict__ KgT, float* __restrict__ Vg)
{
  int bh = blockIdx.y;
  int r = blockIdx.x * 8 + (threadIdx.x >> 5);
  int d = threadIdx.x & 31;
  int b = bh >> 3, h = bh & 7;
  int rn = idx[bh * KTOP + r];                 // kept row
  int cn = idx[(BHN + bh) * KTOP + r];         // kept col
  const float scale = 0.17677669529663687f;    // 1/sqrt(32)
  Qg [((long)bh * KTOP + r) * 32 + d] = qkv[((long)(b * N_PIX + rn)) * 768 + h * 32 + d] * scale;
  KgT[((long)bh * 32 + d) * KTOP + r] = qkv[((long)(b * N_PIX + cn)) * 768 + 256 + h * 32 + d];
  Vg [((long)bh * KTOP + r) * 32 + d] = qkv[((long)(b * N_PIX + cn)) * 768 + 512 + h * 32 + d];
}

// vdiff[bh][d] = v_sum_all - sum over kept cols of Vg
__global__ __launch_bounds__(64) void vdiff_kernel(
    const float* __restrict__ Vg, const float* __restrict__ sums, float* __restrict__ vdiff)
{
  int bh = blockIdx.x; int d = threadIdx.x;
  if (d >= 32) return;
  const float* v = Vg + (long)bh * KTOP * 32 + d;
  float s = 0.f;
  for (int r = 0; r < KTOP; ++r) s += v[(long)r * 32];
  vdiff[bh * 32 + d] = sums[bh * 96 + 64 + d] - s;
}

// default (non-kept rows): o = v_mean
__global__ __launch_bounds__(256) void ofill_kernel(
    const float* __restrict__ sums, float* __restrict__ ofull)
{
  int c = threadIdx.x;
  int b = blockIdx.x / N_PIX;
  int h = c >> 5, d = c & 31;
  ofull[(long)blockIdx.x * 256 + c] = sums[((b << 3) + h) * 96 + 64 + d] * (1.f / (float)N_PIX);
}

// per kept row: in-place S -> exp(S-m); denom = sum + 1728*e^-m ; extra = e^-m
__global__ __launch_bounds__(64) void softprep_kernel(
    float* __restrict__ S, float* __restrict__ denom, float* __restrict__ extra)
{
  int bh = blockIdx.y, row = blockIdx.x;
  float* p = S + ((long)bh * KTOP + row) * KTOP;
  int t = threadIdx.x;
  float m = -1e30f;
  for (int j = t; j < KTOP; j += 64) m = fmaxf(m, p[j]);
  for (int off = 32; off > 0; off >>= 1) m = fmaxf(m, __shfl_down(m, off));
  m = __shfl(m, 0);
  m = fmaxf(m, 0.f);   // pruned cols contribute exp(0) -> max includes 0, matching jax
  float s = 0.f;
  for (int j = t; j < KTOP; j += 64) { float e = expf(p[j] - m); p[j] = e; s += e; }
  for (int off = 32; off > 0; off >>= 1) s += __shfl_down(s, off);
  if (t == 0) {
    float em = expf(-m);
    denom[bh * KTOP + row] = s + (float)(N_PIX - KTOP) * em;
    extra[bh * KTOP + row] = em;
  }
}

// Og[r][d] = (P[r,:]@Vg[:,d] + extra_r*vdiff[d]) / denom_r
__global__ __launch_bounds__(256) void pv_kernel(
    const float* __restrict__ P, const float* __restrict__ Vg,
    const float* __restrict__ vdiff, const float* __restrict__ denom,
    const float* __restrict__ extra, float* __restrict__ Og)
{
  int bh = blockIdx.y;
  int r = blockIdx.x * 8 + (threadIdx.x >> 5);
  int d = threadIdx.x & 31;
  const float* prow = P + ((long)bh * KTOP + r) * KTOP;
  const float* v = Vg + (long)bh * KTOP * 32 + d;
  float acc = 0.f;
#pragma unroll 4
  for (int j = 0; j < KTOP; ++j) acc += prow[j] * v[(long)j * 32];
  Og[((long)bh * KTOP + r) * 32 + d] =
      (acc + extra[bh * KTOP + r] * vdiff[bh * 32 + d]) / denom[bh * KTOP + r];
}

__global__ __launch_bounds__(256) void scatter_kernel(
    const float* __restrict__ Og, const int* __restrict__ idx, float* __restrict__ ofull)
{
  int bh = blockIdx.y;
  int r = blockIdx.x * 8 + (threadIdx.x >> 5);
  int d = threadIdx.x & 31;
  int b = bh >> 3, h = bh & 7;
  int n = idx[bh * KTOP + r];
  ofull[((long)(b * N_PIX + n)) * 256 + h * 32 + d] = Og[((long)bh * KTOP + r) * 32 + d];
}

// ======================= depthwise 3x3 (NCHW in -> NHWC out) =========
__global__ __launch_bounds__(256) void dwconv_kernel(
    const float* __restrict__ x, const float* __restrict__ w,
    const float* __restrict__ bias, float* __restrict__ out_nhwc)
{
  int pix = blockIdx.x;                // b*2304 + y*48 + xx
  int b = pix / N_PIX; int p = pix - b * N_PIX;
  int y = p / 48, xx = p - y * 48;
  int c = threadIdx.x;
  const float* xp = x + ((long)b * 256 + c) * N_PIX;
  float acc = bias[c];
#pragma unroll
  for (int ky = 0; ky < 3; ++ky) {
    int yy = y + ky - 1; if (yy < 0 || yy >= 48) continue;
#pragma unroll
    for (int kx = 0; kx < 3; ++kx) {
      int xc = xx + kx - 1; if (xc < 0 || xc >= 48) continue;
      acc += w[c * 9 + ky * 3 + kx] * xp[yy * 48 + xc];
    }
  }
  out_nhwc[(long)pix * 256 + c] = acc;
}

// ======================= generic small transpose ======================
__global__ __launch_bounds__(256) void transpose_kernel(
    const float* __restrict__ in, float* __restrict__ out, int R, int Cc)
{
  int i = blockIdx.x * 256 + threadIdx.x;
  if (i < R * Cc) { int r = i / Cc, c = i - r * Cc; out[c * R + r] = in[i]; }
}

// ======================= spatial gate 7x7 (32ch -> 1) =================
__global__ __launch_bounds__(64) void sg2_kernel(
    const float* __restrict__ sga, const float* __restrict__ w,
    const float* __restrict__ b1, float* __restrict__ sgate)
{
  __shared__ float ws[32 * 49];
  int by = blockIdx.x; int b = by / 48, y = by - b * 48;
  int t = threadIdx.x;
  for (int i = t; i < 32 * 49; i += 64) ws[i] = w[i];
  __syncthreads();
  if (t >= 48) return;
  float acc = b1[0];
  for (int ky = 0; ky < 7; ++ky) {
    int yy = y + ky - 3; if (yy < 0 || yy >= 48) continue;
    for (int kx = 0; kx < 7; ++kx) {
      int xc = t + kx - 3; if (xc < 0 || xc >= 48) continue;
      const float* sp = sga + ((long)(b * N_PIX + yy * 48 + xc)) * 32;
      float a = 0.f;
#pragma unroll
      for (int g = 0; g < 32; g += 4) {
        float4 vv = *(const float4*)(sp + g);
        a += ws[(g + 0) * 49 + ky * 7 + kx] * vv.x;
        a += ws[(g + 1) * 49 + ky * 7 + kx] * vv.y;
        a += ws[(g + 2) * 49 + ky * 7 + kx] * vv.z;
        a += ws[(g + 3) * 49 + ky * 7 + kx] * vv.w;
      }
      acc += a;
    }
  }
  sgate[b * N_PIX + y * 48 + t] = 1.f / (1.f + expf(-acc));
}

// ======================= channel gate =================================
__global__ __launch_bounds__(256) void cgmean_kernel(
    const float* __restrict__ xs, float* __restrict__ cgm)
{
  int chunk = blockIdx.x, b = blockIdx.y, c = threadIdx.x;
  const float* p = xs + ((long)(b * N_PIX + chunk * 64)) * 256 + c;
  float s = 0.f;
  for (int t = 0; t < 64; ++t) { s += *p; p += 256; }
  atomicAdd(&cgm[b * 256 + c], s);
}

__global__ __launch_bounds__(256) void cgmlp_kernel(
    const float* __restrict__ cgm, const float* __restrict__ w1, const float* __restrict__ b1,
    const float* __restrict__ w2, const float* __restrict__ b2, float* __restrict__ cgate)
{
  int b = blockIdx.x; int t = threadIdx.x;
  __shared__ float m[256];
  __shared__ float a[32];
  m[t] = cgm[b * 256 + t] * (1.f / (float)N_PIX);
  __syncthreads();
  if (t < 32) {
    float s = b1[t];
    for (int c = 0; c < 256; ++c) s += w1[t * 256 + c] * m[c];
    a[t] = s / (1.f + expf(-s));
  }
  __syncthreads();
  float s = b2[t];
#pragma unroll
  for (int g = 0; g < 32; ++g) s += w2[t * 32 + g] * a[g];
  cgate[b * 256 + t] = 1.f / (1.f + expf(-s));
}

// ======================= x2 = x + gamma1*(xs*sg*cg) (NHWC out) ========
__global__ __launch_bounds__(256) void x2_kernel(
    const float* __restrict__ x, const float* __restrict__ xs,
    const float* __restrict__ sgate, const float* __restrict__ cgate,
    const float* __restrict__ gamma1, float* __restrict__ x2)
{
  int pix = blockIdx.x; int b = pix / N_PIX, p = pix - b * N_PIX;
  int c = threadIdx.x;
  float xv = x[((long)b * 256 + c) * N_PIX + p];
  float v = xs[(long)pix * 256 + c] * sgate[pix] * cgate[b * 256 + c];
  x2[(long)pix * 256 + c] = xv + gamma1[0] * v;
}

// ======================================================================
extern "C" void kernel_launch(void* const* d_in, const int* in_sizes, int n_in,
                              void* d_out, int out_size, void* d_ws, size_t ws_size,
                              hipStream_t stream) {
  (void)in_sizes; (void)n_in; (void)out_size; (void)ws_size;
  const float* x      = (const float*)d_in[0];
  const float* qkv_w  = (const float*)d_in[1];
  const float* out_w  = (const float*)d_in[2];
  const float* ln1_g  = (const float*)d_in[3];
  const float* ln1_b  = (const float*)d_in[4];
  const float* ln2_g  = (const float*)d_in[5];
  const float* ln2_b  = (const float*)d_in[6];
  const float* dw_w   = (const float*)d_in[7];
  const float* dw_b   = (const float*)d_in[8];
  const float* pw_w   = (const float*)d_in[9];
  const float* pw_b   = (const float*)d_in[10];
  const float* sg1_w  = (const float*)d_in[11];
  const float* sg1_b  = (const float*)d_in[12];
  const float* sg2_w  = (const float*)d_in[13];
  const float* sg2_b  = (const float*)d_in[14];
  const float* cg1_w  = (const float*)d_in[15];
  const float* cg1_b  = (const float*)d_in[16];
  const float* cg2_w  = (const float*)d_in[17];
  const float* cg2_b  = (const float*)d_in[18];
  const float* ff_w1  = (const float*)d_in[19];
  const float* ff_b1  = (const float*)d_in[20];
  const float* ff_w2  = (const float*)d_in[21];
  const float* ff_b2  = (const float*)d_in[22];
  const float* gamma1 = (const float*)d_in[23];
  const float* gamma2 = (const float*)d_in[24];
  float* out = (float*)d_out;
  float* ws  = (float*)d_ws;

  // -------- workspace layout (floats). Total 15,085,056 fl = 57.6 MB --------
  float* qkv   = ws + 0;          // 3,538,944 ; later reused as dwc (NHWC)
  float* xa    = ws + 3538944;    // 1,179,648 ; later reused as attn_out
  float* Sbuf  = ws + 4718592;    // 5,308,416 ; later reused as h [4608,1024]
  float* ofull = ws + 10027008;   // 1,179,648 ; later reused as normed
  float* xs    = ws + 11206656;   // 1,179,648
  float* x2    = ws + 12386304;   // 1,179,648
  float* Qg    = ws + 13565952;   // 294,912
  float* KgT   = ws + 13860864;   // 294,912
  float* Vg    = ws + 14155776;   // 294,912
  float* Og    = ws + 14450688;   // 294,912
  float* scores= ws + 14745600;   // 73,728 (rows then cols)
  float* sums  = ws + 14819328;   // 1,536
  float* vdiff = ws + 14820864;   // 512
  float* denom = ws + 14821376;   // 9,216
  float* extra = ws + 14830592;   // 9,216
  float* sga   = ws + 14839808;   // 147,456
  float* sgate = ws + 14987264;   // 4,608
  float* cgm   = ws + 14991872;   // 512
  float* cgate = ws + 14992384;   // 512
  float* pwT   = ws + 14992896;   // 65,536
  float* sg1T  = ws + 15058432;   // 8,192
  int*   idxb  = (int*)(ws + 15066624); // 18,432 ints
  float* dwc      = qkv;     // alias (qkv dead after gather)
  float* attn_out = xa;      // alias (xa dead after qkv GEMM)
  float* h        = Sbuf;    // alias (S dead after PV)
  float* normed   = ofull;   // alias (ofull dead after out-proj)

  dim3 blk(256);
  hipMemsetAsync(sums, 0, 1536 * sizeof(float), stream);
  hipMemsetAsync(cgm, 0, 512 * sizeof(float), stream);

  // ---- attention branch ----
  ln_kernel<<<dim3(NROWS), blk, 0, stream>>>(x, xa, ln1_g, ln1_b, N_PIX, 1);
  gemm_kernel<0><<<dim3(12, 72, 1), blk, 0, stream>>>(xa, qkv_w, qkv, NROWS, 768, 256,
      nullptr, nullptr, nullptr, 0, 0, 0);
  qkv_sums_kernel<<<dim3(BHN, 16), dim3(128), 0, stream>>>(qkv, sums);
  score_kernel<<<dim3(144), blk, 0, stream>>>(qkv, sums, scores, scores + BHN * N_PIX);
  topk_kernel<<<dim3(BHN, 2), blk, 0, stream>>>(scores, idxb);
  gather_kernel<<<dim3(72, BHN), blk, 0, stream>>>(qkv, idxb, Qg, KgT, Vg);
  vdiff_kernel<<<dim3(BHN), dim3(64), 0, stream>>>(Vg, sums, vdiff);
  ofill_kernel<<<dim3(NROWS), blk, 0, stream>>>(sums, ofull);
  gemm_kernel<0><<<dim3(9, 9, BHN), blk, 0, stream>>>(Qg, KgT, Sbuf, KTOP, KTOP, 32,
      nullptr, nullptr, nullptr, (long)KTOP * 32, (long)32 * KTOP, (long)KTOP * KTOP);
  softprep_kernel<<<dim3(KTOP, BHN), dim3(64), 0, stream>>>(Sbuf, denom, extra);
  pv_kernel<<<dim3(72, BHN), blk, 0, stream>>>(Sbuf, Vg, vdiff, denom, extra, Og);
  scatter_kernel<<<dim3(72, BHN), blk, 0, stream>>>(Og, idxb, ofull);
  gemm_kernel<0><<<dim3(4, 72, 1), blk, 0, stream>>>(ofull, out_w, attn_out, NROWS, 256, 256,
      nullptr, nullptr, nullptr, 0, 0, 0);

  // ---- conv branch (dwc overwrites qkv region — qkv dead now) ----
  dwconv_kernel<<<dim3(NROWS), blk, 0, stream>>>(x, dw_w, dw_b, dwc);
  transpose_kernel<<<dim3(256), blk, 0, stream>>>(pw_w, pwT, 256, 256);
  transpose_kernel<<<dim3(32), blk, 0, stream>>>(sg1_w, sg1T, 32, 256);
  gemm_kernel<0><<<dim3(4, 72, 1), blk, 0, stream>>>(dwc, pwT, xs, NROWS, 256, 256,
      pw_b, attn_out, nullptr, 0, 0, 0);

  // ---- gates ----
  gemm_kernel<2><<<dim3(1, 72, 1), blk, 0, stream>>>(xs, sg1T, sga, NROWS, 32, 256,
      sg1_b, nullptr, nullptr, 0, 0, 0);
  sg2_kernel<<<dim3(96), dim3(64), 0, stream>>>(sga, sg2_w, sg2_b, sgate);
  cgmean_kernel<<<dim3(36, 2), blk, 0, stream>>>(xs, cgm);
  cgmlp_kernel<<<dim3(2), blk, 0, stream>>>(cgm, cg1_w, cg1_b, cg2_w, cg2_b, cgate);
  x2_kernel<<<dim3(NROWS), blk, 0, stream>>>(x, xs, sgate, cgate, gamma1, x2);

  // ---- FFN ----
  ln_kernel<<<dim3(NROWS), blk, 0, stream>>>(x2, normed, ln2_g, ln2_b, 1, 256);
  gemm_kernel<1><<<dim3(16, 72, 1), blk, 0, stream>>>(normed, ff_w1, h, NROWS, 1024, 256,
      ff_b1, nullptr, nullptr, 0, 0, 0);
  gemm_kernel<3><<<dim3(4, 72, 1), blk, 0, stream>>>(h, ff_w2, out, NROWS, 256, 1024,
      ff_b2, x2, gamma2, 0, 0, 0);
}

// Round 2
// 469.448 us; speedup vs baseline: 1.3088x; 1.3088x over previous
//
#include <hip/hip_runtime.h>
#include <math.h>

#define N_PIX 2304
#define CCH   256
#define BHN   16     // B * NHEAD
#define KTOP  576
#define NROWS 4608   // B * N_PIX

typedef unsigned short u16;
typedef __attribute__((ext_vector_type(8))) short short8v;   // 8 bf16
typedef __attribute__((ext_vector_type(4))) float floatx4;

__device__ __forceinline__ u16 f2b(float f) {
  unsigned int u = __float_as_uint(f);
  return (u16)((u + 0x7fffu + ((u >> 16) & 1u)) >> 16);      // RNE
}

__device__ __forceinline__ void async16(const void* g, void* l) {
  __builtin_amdgcn_global_load_lds(
      (const __attribute__((address_space(1))) unsigned int*)g,
      (__attribute__((address_space(3))) unsigned int*)l, 16, 0, 0);
}

// ======================= LayerNorm (over C=256) -> bf16 ================
// in layout: offset = b*C*N + n*rowStride + c*elemStride
__global__ __launch_bounds__(256) void ln_kernel(
    const float* __restrict__ in, u16* __restrict__ out,
    const float* __restrict__ g, const float* __restrict__ bvec,
    int elemStride, int rowStride)
{
  int r = blockIdx.x;
  int b = r / N_PIX, n = r - b * N_PIX;
  const float* p = in + (long)b * CCH * N_PIX + (long)n * rowStride;
  int c = threadIdx.x;
  float v = p[(long)c * elemStride];
  __shared__ float red[256];
  red[c] = v; __syncthreads();
  for (int off = 128; off > 0; off >>= 1) { if (c < off) red[c] += red[c + off]; __syncthreads(); }
  float mu = red[0] * (1.f / 256.f);
  __syncthreads();
  float dv = v - mu;
  red[c] = dv * dv; __syncthreads();
  for (int off = 128; off > 0; off >>= 1) { if (c < off) red[c] += red[c + off]; __syncthreads(); }
  float var = red[0] * (1.f / 256.f);
  out[(long)r * CCH + c] = f2b(dv * rsqrtf(var + 1e-6f) * g[c] + bvec[c]);
}

// ======================= weight cast kernels ==========================
// BT[n*K + k] = bf16(W[k*N + n])
__global__ __launch_bounds__(256) void castT_kernel(
    const float* __restrict__ W, u16* __restrict__ BT, int K, int N)
{
  int i = blockIdx.x * 256 + threadIdx.x;
  if (i < K * N) { int k = i / N, n = i - k * N; BT[(long)n * K + k] = f2b(W[i]); }
}
__global__ __launch_bounds__(256) void cast_kernel(
    const float* __restrict__ W, u16* __restrict__ BT, int total, int padTotal)
{
  int i = blockIdx.x * 256 + threadIdx.x;
  if (i < total) BT[i] = f2b(W[i]);
  else if (i < padTotal) BT[i] = 0;
}

// ======================= bf16 MFMA GEMM ===============================
// C[M,N] = A[M,K](bf16) @ BT[N,K](bf16)^T.  Block tile 128x64, BK=32.
// grid = (N/64, M/128). 4 waves; wave w owns rows [w*32, w*32+32).
// EPI 0: C fp32 = acc
// EPI 2: t=acc+bias+add -> C fp32 AND C2 bf16
// EPI 3: silu(acc+bias) -> C fp32, only cols < nvalid
// EPI 4: gelu(acc+bias) -> C2 bf16
// EPI 5: out NCHW = add(row-major,256) + gamma*(acc+bias)
template<int EPI>
__global__ __launch_bounds__(256) void mgemm(
    const u16* __restrict__ A, const u16* __restrict__ BT,
    float* __restrict__ C, u16* __restrict__ C2,
    int K, int ldc, int nvalid,
    const float* __restrict__ bias, const float* __restrict__ add,
    const float* __restrict__ gamma)
{
  __shared__ u16 Als[128 * 32];
  __shared__ u16 Bls[64 * 32];
  int tid = threadIdx.x;
  int w = tid >> 6, lane = tid & 63;
  int row0 = blockIdx.y * 128, col0 = blockIdx.x * 64;
  const u16* Abase = A + (long)row0 * K;
  const u16* Bbase = BT + (long)col0 * K;
  int q = lane >> 4, l15 = lane & 15;

  floatx4 acc[2][4];
#pragma unroll
  for (int mi = 0; mi < 2; ++mi)
#pragma unroll
    for (int ni = 0; ni < 4; ++ni) acc[mi][ni] = (floatx4)0.f;

  // precompute lane-chunk coords
  int ccA0 = w * 128 + lane;            // A chunks issue 0
  int ccA1 = ccA0 + 64;                 // A chunks issue 1
  int ccB  = w * 64 + lane;
  int rA0 = ccA0 >> 2, kA0 = (ccA0 & 3) << 3;
  int rA1 = ccA1 >> 2, kA1 = (ccA1 & 3) << 3;
  int rB  = ccB >> 2,  kB  = (ccB & 3) << 3;

  for (int k0 = 0; k0 < K; k0 += 32) {
    async16(Abase + (long)rA0 * K + k0 + kA0, &Als[ccA0 * 8]);
    async16(Abase + (long)rA1 * K + k0 + kA1, &Als[ccA1 * 8]);
    async16(Bbase + (long)rB  * K + k0 + kB,  &Bls[ccB * 8]);
    __syncthreads();
    short8v a0 = *(const short8v*)&Als[(w * 32 + l15) * 32 + q * 8];
    short8v a1 = *(const short8v*)&Als[(w * 32 + 16 + l15) * 32 + q * 8];
#pragma unroll
    for (int ni = 0; ni < 4; ++ni) {
      short8v b = *(const short8v*)&Bls[(ni * 16 + l15) * 32 + q * 8];
      acc[0][ni] = __builtin_amdgcn_mfma_f32_16x16x32_bf16(a0, b, acc[0][ni], 0, 0, 0);
      acc[1][ni] = __builtin_amdgcn_mfma_f32_16x16x32_bf16(a1, b, acc[1][ni], 0, 0, 0);
    }
    __syncthreads();
  }

  float g2 = (EPI == 5) ? gamma[0] : 0.f;
#pragma unroll
  for (int mi = 0; mi < 2; ++mi) {
#pragma unroll
    for (int ni = 0; ni < 4; ++ni) {
      int c = col0 + ni * 16 + l15;
      int rbase = row0 + w * 32 + mi * 16 + q * 4;
#pragma unroll
      for (int reg = 0; reg < 4; ++reg) {
        long row = rbase + reg;
        float v = acc[mi][ni][reg];
        if (EPI == 0) {
          C[row * ldc + c] = v;
        } else if (EPI == 2) {
          float t = v + bias[c] + add[row * ldc + c];
          C[row * ldc + c] = t;
          C2[row * ldc + c] = f2b(t);
        } else if (EPI == 3) {
          if (c < nvalid) {
            float t = v + bias[c];
            C[row * (long)nvalid + c] = t / (1.f + expf(-t));
          }
        } else if (EPI == 4) {
          float t = v + bias[c];
          t = 0.5f * t * (1.f + erff(t * 0.70710678118654752f));
          C2[row * ldc + c] = f2b(t);
        } else if (EPI == 5) {
          float t = add[row * 256 + c] + g2 * (v + bias[c]);
          int bb = (int)(row / N_PIX); int p = (int)(row - (long)bb * N_PIX);
          C[((long)bb * 256 + c) * N_PIX + p] = t;
        }
      }
    }
  }
}

// ======================= fp32 GEMM 64x64x16 (kept for batched S) ======
template<int EPI>
__global__ __launch_bounds__(256) void gemm_kernel(
    const float* __restrict__ A, const float* __restrict__ B, float* __restrict__ C,
    int M, int N, int K,
    const float* __restrict__ bias, const float* __restrict__ add,
    const float* __restrict__ gamma,
    long sA, long sB, long sC)
{
  __shared__ float As[16][68];
  __shared__ float Bs[16][68];
  int bz = blockIdx.z;
  A += sA * bz; B += sB * bz; C += sC * bz;
  int tid = threadIdx.x;
  int tx = tid & 15, ty = tid >> 4;
  int row0 = blockIdx.y * 64, col0 = blockIdx.x * 64;
  int ar = tid >> 2, ac = (tid & 3) << 2;
  int br = tid >> 4, bc = (tid & 15) << 2;
  float acc[4][4] = {{0.f}};
  const float* Aptr = A + (long)(row0 + ar) * K + ac;
  const float* Bptr = B + (long)br * N + col0 + bc;
  bool bvalid = (col0 + bc) < N;
  for (int k0 = 0; k0 < K; k0 += 16) {
    float4 av = *(const float4*)(Aptr);
    Aptr += 16;
    float4 bv = make_float4(0.f, 0.f, 0.f, 0.f);
    if (bvalid) bv = *(const float4*)(Bptr);
    Bptr += (long)16 * N;
    As[ac + 0][ar] = av.x; As[ac + 1][ar] = av.y; As[ac + 2][ar] = av.z; As[ac + 3][ar] = av.w;
    *(float4*)&Bs[br][bc] = bv;
    __syncthreads();
#pragma unroll
    for (int kk = 0; kk < 16; ++kk) {
      float4 a = *(const float4*)&As[kk][ty << 2];
      float4 b = *(const float4*)&Bs[kk][tx << 2];
      acc[0][0] += a.x * b.x; acc[0][1] += a.x * b.y; acc[0][2] += a.x * b.z; acc[0][3] += a.x * b.w;
      acc[1][0] += a.y * b.x; acc[1][1] += a.y * b.y; acc[1][2] += a.y * b.z; acc[1][3] += a.y * b.w;
      acc[2][0] += a.z * b.x; acc[2][1] += a.z * b.y; acc[2][2] += a.z * b.z; acc[2][3] += a.z * b.w;
      acc[3][0] += a.w * b.x; acc[3][1] += a.w * b.y; acc[3][2] += a.w * b.z; acc[3][3] += a.w * b.w;
    }
    __syncthreads();
  }
#pragma unroll
  for (int i = 0; i < 4; ++i) {
    long r = row0 + (ty << 2) + i;
#pragma unroll
    for (int j = 0; j < 4; ++j) {
      int c = col0 + (tx << 2) + j;
      if (c >= N) continue;
      C[r * N + c] = acc[i][j];
    }
  }
}

// ======================= q/k/v sums per (b,h) =======================
__global__ __launch_bounds__(128) void qkv_sums_kernel(
    const float* __restrict__ qkv, float* __restrict__ acc)
{
  int bh = blockIdx.x, chunk = blockIdx.y;
  int j = threadIdx.x;
  if (j >= 96) return;
  int b = bh >> 3, h = bh & 7;
  int col = (j >> 5) * 256 + h * 32 + (j & 31);
  int n0 = chunk * 144;
  const float* p = qkv + ((long)(b * N_PIX + n0)) * 768 + col;
  float s = 0.f;
  for (int t = 0; t < 144; ++t) { s += *p; p += 768; }
  atomicAdd(&acc[bh * 96 + j], s);
}

// ======================= rank-1 row/col scores =======================
__global__ __launch_bounds__(256) void score_kernel(
    const float* __restrict__ qkv, const float* __restrict__ acc,
    float* __restrict__ rs, float* __restrict__ cs)
{
  int idx = blockIdx.x * 256 + threadIdx.x;
  if (idx >= BHN * N_PIX) return;
  int bh = idx / N_PIX, n = idx - bh * N_PIX;
  int b = bh >> 3, h = bh & 7;
  const float* qp = qkv + ((long)(b * N_PIX + n)) * 768 + h * 32;
  const float* qs = acc + bh * 96;
  const float* ks = acc + bh * 96 + 32;
  float r = 0.f, c = 0.f;
#pragma unroll
  for (int d = 0; d < 32; ++d) { r += qp[d] * ks[d]; c += qp[256 + d] * qs[d]; }
  rs[idx] = r; cs[idx] = c;
}

// ======================= exact top-576 (radix select, jax tie rule) ===
__device__ __forceinline__ unsigned int excl_scan256(unsigned int val, unsigned int* tmp, int tid) {
  tmp[tid] = val; __syncthreads();
#pragma unroll
  for (int off = 1; off < 256; off <<= 1) {
    unsigned int t = (tid >= off) ? tmp[tid - off] : 0u;
    __syncthreads();
    tmp[tid] += t;
    __syncthreads();
  }
  unsigned int incl = tmp[tid];
  __syncthreads();
  return incl - val;
}

__global__ __launch_bounds__(256) void topk_kernel(
    const float* __restrict__ scores, int* __restrict__ out_idx)
{
  int bh = blockIdx.x;
  int which = blockIdx.y;
  const float* s = scores + (long)(which * BHN + bh) * N_PIX;
  int* out = out_idx + (which * BHN + bh) * KTOP;
  __shared__ unsigned int u[N_PIX];
  __shared__ unsigned int hist[256];
  __shared__ unsigned int tmp[256];
  __shared__ unsigned int bc0, bc1;
  __shared__ unsigned int run_sel, run_eq;
  int tid = threadIdx.x;
  for (int i = tid; i < N_PIX; i += 256) {
    unsigned int b = __float_as_uint(s[i]);
    u[i] = (b & 0x80000000u) ? ~b : (b | 0x80000000u);
  }
  __syncthreads();
  unsigned int prefix = 0u, kRem = KTOP;
  for (int pass = 0; pass < 4; ++pass) {
    int shift = 24 - pass * 8;
    hist[tid] = 0u;
    __syncthreads();
    unsigned int mask = (pass == 0) ? 0u : (0xFFFFFFFFu << (shift + 8));
    for (int i = tid; i < N_PIX; i += 256) {
      unsigned int v = u[i];
      if ((v & mask) == prefix) atomicAdd(&hist[(v >> shift) & 255u], 1u);
    }
    __syncthreads();
    if (tid == 0) {
      unsigned int cum = 0u, sel = 0u;
      for (int bv = 255; bv >= 0; --bv) {
        unsigned int cb = hist[bv];
        if (cum + cb >= kRem) { sel = (unsigned int)bv; break; }
        cum += cb;
      }
      bc0 = sel; bc1 = cum;
    }
    __syncthreads();
    prefix |= (bc0 << shift);
    kRem -= bc1;
    __syncthreads();
  }
  unsigned int T = prefix;
  if (tid == 0) { run_sel = 0u; run_eq = 0u; }
  __syncthreads();
  for (int c0 = 0; c0 < N_PIX; c0 += 256) {
    int i = c0 + tid;
    unsigned int v = u[i];
    unsigned int isGt = (v > T) ? 1u : 0u;
    unsigned int isEq = (v == T) ? 1u : 0u;
    unsigned int eqPre = excl_scan256(isEq, tmp, tid);
    unsigned int eqRank = run_eq + eqPre;
    unsigned int selF = (isGt || (isEq && eqRank < kRem)) ? 1u : 0u;
    unsigned int selPre = excl_scan256(selF, tmp, tid);
    unsigned int pos = run_sel + selPre;
    if (selF && pos < KTOP) out[pos] = i;
    __syncthreads();
    if (tid == 255) { run_sel += selPre + selF; run_eq += eqPre + isEq; }
    __syncthreads();
  }
}

// ======================= gather kept rows/cols =======================
__global__ __launch_bounds__(256) void gather_kernel(
    const float* __restrict__ qkv, const int* __restrict__ idx,
    float* __restrict__ Qg, float* __restrict__ KgT, float* __restrict__ Vg)
{
  int bh = blockIdx.y;
  int r = blockIdx.x * 8 + (threadIdx.x >> 5);
  int d = threadIdx.x & 31;
  int b = bh >> 3, h = bh & 7;
  int rn = idx[bh * KTOP + r];
  int cn = idx[(BHN + bh) * KTOP + r];
  const float scale = 0.17677669529663687f;
  Qg [((long)bh * KTOP + r) * 32 + d] = qkv[((long)(b * N_PIX + rn)) * 768 + h * 32 + d] * scale;
  KgT[((long)bh * 32 + d) * KTOP + r] = qkv[((long)(b * N_PIX + cn)) * 768 + 256 + h * 32 + d];
  Vg [((long)bh * KTOP + r) * 32 + d] = qkv[((long)(b * N_PIX + cn)) * 768 + 512 + h * 32 + d];
}

__global__ __launch_bounds__(64) void vdiff_kernel(
    const float* __restrict__ Vg, const float* __restrict__ sums, float* __restrict__ vdiff)
{
  int bh = blockIdx.x; int d = threadIdx.x;
  if (d >= 32) return;
  const float* v = Vg + (long)bh * KTOP * 32 + d;
  float s = 0.f;
  for (int r = 0; r < KTOP; ++r) s += v[(long)r * 32];
  vdiff[bh * 32 + d] = sums[bh * 96 + 64 + d] - s;
}

// default (non-kept rows): o = v_mean  -> bf16
__global__ __launch_bounds__(256) void ofill_kernel(
    const float* __restrict__ sums, u16* __restrict__ ofull)
{
  int c = threadIdx.x;
  int b = blockIdx.x / N_PIX;
  int h = c >> 5, d = c & 31;
  ofull[(long)blockIdx.x * 256 + c] = f2b(sums[((b << 3) + h) * 96 + 64 + d] * (1.f / (float)N_PIX));
}

__global__ __launch_bounds__(64) void softprep_kernel(
    float* __restrict__ S, float* __restrict__ denom, float* __restrict__ extra)
{
  int bh = blockIdx.y, row = blockIdx.x;
  float* p = S + ((long)bh * KTOP + row) * KTOP;
  int t = threadIdx.x;
  float m = -1e30f;
  for (int j = t; j < KTOP; j += 64) m = fmaxf(m, p[j]);
  for (int off = 32; off > 0; off >>= 1) m = fmaxf(m, __shfl_down(m, off));
  m = __shfl(m, 0);
  m = fmaxf(m, 0.f);
  float s = 0.f;
  for (int j = t; j < KTOP; j += 64) { float e = expf(p[j] - m); p[j] = e; s += e; }
  for (int off = 32; off > 0; off >>= 1) s += __shfl_down(s, off);
  if (t == 0) {
    float em = expf(-m);
    denom[bh * KTOP + row] = s + (float)(N_PIX - KTOP) * em;
    extra[bh * KTOP + row] = em;
  }
}

__global__ __launch_bounds__(256) void pv_kernel(
    const float* __restrict__ P, const float* __restrict__ Vg,
    const float* __restrict__ vdiff, const float* __restrict__ denom,
    const float* __restrict__ extra, float* __restrict__ Og)
{
  int bh = blockIdx.y;
  int r = blockIdx.x * 8 + (threadIdx.x >> 5);
  int d = threadIdx.x & 31;
  const float* prow = P + ((long)bh * KTOP + r) * KTOP;
  const float* v = Vg + (long)bh * KTOP * 32 + d;
  float acc = 0.f;
#pragma unroll 4
  for (int j = 0; j < KTOP; ++j) acc += prow[j] * v[(long)j * 32];
  Og[((long)bh * KTOP + r) * 32 + d] =
      (acc + extra[bh * KTOP + r] * vdiff[bh * 32 + d]) / denom[bh * KTOP + r];
}

__global__ __launch_bounds__(256) void scatter_kernel(
    const float* __restrict__ Og, const int* __restrict__ idx, u16* __restrict__ ofull)
{
  int bh = blockIdx.y;
  int r = blockIdx.x * 8 + (threadIdx.x >> 5);
  int d = threadIdx.x & 31;
  int b = bh >> 3, h = bh & 7;
  int n = idx[bh * KTOP + r];
  ofull[((long)(b * N_PIX + n)) * 256 + h * 32 + d] = f2b(Og[((long)bh * KTOP + r) * 32 + d]);
}

// ======================= depthwise 3x3 (NCHW in -> NHWC bf16 out) =====
__global__ __launch_bounds__(256) void dwconv_kernel(
    const float* __restrict__ x, const float* __restrict__ w,
    const float* __restrict__ bias, u16* __restrict__ out_nhwc)
{
  int pix = blockIdx.x;
  int b = pix / N_PIX; int p = pix - b * N_PIX;
  int y = p / 48, xx = p - y * 48;
  int c = threadIdx.x;
  const float* xp = x + ((long)b * 256 + c) * N_PIX;
  float acc = bias[c];
#pragma unroll
  for (int ky = 0; ky < 3; ++ky) {
    int yy = y + ky - 1; if (yy < 0 || yy >= 48) continue;
#pragma unroll
    for (int kx = 0; kx < 3; ++kx) {
      int xc = xx + kx - 1; if (xc < 0 || xc >= 48) continue;
      acc += w[c * 9 + ky * 3 + kx] * xp[yy * 48 + xc];
    }
  }
  out_nhwc[(long)pix * 256 + c] = f2b(acc);
}

// ======================= spatial gate 7x7 (32ch -> 1) =================
__global__ __launch_bounds__(64) void sg2_kernel(
    const float* __restrict__ sga, const float* __restrict__ w,
    const float* __restrict__ b1, float* __restrict__ sgate)
{
  __shared__ float ws[32 * 49];
  int by = blockIdx.x; int b = by / 48, y = by - b * 48;
  int t = threadIdx.x;
  for (int i = t; i < 32 * 49; i += 64) ws[i] = w[i];
  __syncthreads();
  if (t >= 48) return;
  float acc = b1[0];
  for (int ky = 0; ky < 7; ++ky) {
    int yy = y + ky - 3; if (yy < 0 || yy >= 48) continue;
    for (int kx = 0; kx < 7; ++kx) {
      int xc = t + kx - 3; if (xc < 0 || xc >= 48) continue;
      const float* sp = sga + ((long)(b * N_PIX + yy * 48 + xc)) * 32;
      float a = 0.f;
#pragma unroll
      for (int g = 0; g < 32; g += 4) {
        float4 vv = *(const float4*)(sp + g);
        a += ws[(g + 0) * 49 + ky * 7 + kx] * vv.x;
        a += ws[(g + 1) * 49 + ky * 7 + kx] * vv.y;
        a += ws[(g + 2) * 49 + ky * 7 + kx] * vv.z;
        a += ws[(g + 3) * 49 + ky * 7 + kx] * vv.w;
      }
      acc += a;
    }
  }
  sgate[b * N_PIX + y * 48 + t] = 1.f / (1.f + expf(-acc));
}

// ======================= channel gate =================================
__global__ __launch_bounds__(256) void cgmean_kernel(
    const float* __restrict__ xs, float* __restrict__ cgm)
{
  int chunk = blockIdx.x, b = blockIdx.y, c = threadIdx.x;
  const float* p = xs + ((long)(b * N_PIX + chunk * 64)) * 256 + c;
  float s = 0.f;
  for (int t = 0; t < 64; ++t) { s += *p; p += 256; }
  atomicAdd(&cgm[b * 256 + c], s);
}

__global__ __launch_bounds__(256) void cgmlp_kernel(
    const float* __restrict__ cgm, const float* __restrict__ w1, const float* __restrict__ b1,
    const float* __restrict__ w2, const float* __restrict__ b2, float* __restrict__ cgate)
{
  int b = blockIdx.x; int t = threadIdx.x;
  __shared__ float m[256];
  __shared__ float a[32];
  m[t] = cgm[b * 256 + t] * (1.f / (float)N_PIX);
  __syncthreads();
  if (t < 32) {
    float s = b1[t];
    for (int c = 0; c < 256; ++c) s += w1[t * 256 + c] * m[c];
    a[t] = s / (1.f + expf(-s));
  }
  __syncthreads();
  float s = b2[t];
#pragma unroll
  for (int g = 0; g < 32; ++g) s += w2[t * 32 + g] * a[g];
  cgate[b * 256 + t] = 1.f / (1.f + expf(-s));
}

// ======================= x2 = x + gamma1*(xs*sg*cg) (NHWC out) ========
__global__ __launch_bounds__(256) void x2_kernel(
    const float* __restrict__ x, const float* __restrict__ xs,
    const float* __restrict__ sgate, const float* __restrict__ cgate,
    const float* __restrict__ gamma1, float* __restrict__ x2)
{
  int pix = blockIdx.x; int b = pix / N_PIX, p = pix - b * N_PIX;
  int c = threadIdx.x;
  float xv = x[((long)b * 256 + c) * N_PIX + p];
  float v = xs[(long)pix * 256 + c] * sgate[pix] * cgate[b * 256 + c];
  x2[(long)pix * 256 + c] = xv + gamma1[0] * v;
}

// ======================================================================
extern "C" void kernel_launch(void* const* d_in, const int* in_sizes, int n_in,
                              void* d_out, int out_size, void* d_ws, size_t ws_size,
                              hipStream_t stream) {
  (void)in_sizes; (void)n_in; (void)out_size; (void)ws_size;
  const float* x      = (const float*)d_in[0];
  const float* qkv_w  = (const float*)d_in[1];
  const float* out_w  = (const float*)d_in[2];
  const float* ln1_g  = (const float*)d_in[3];
  const float* ln1_b  = (const float*)d_in[4];
  const float* ln2_g  = (const float*)d_in[5];
  const float* ln2_b  = (const float*)d_in[6];
  const float* dw_w   = (const float*)d_in[7];
  const float* dw_b   = (const float*)d_in[8];
  const float* pw_w   = (const float*)d_in[9];
  const float* pw_b   = (const float*)d_in[10];
  const float* sg1_w  = (const float*)d_in[11];
  const float* sg1_b  = (const float*)d_in[12];
  const float* sg2_w  = (const float*)d_in[13];
  const float* sg2_b  = (const float*)d_in[14];
  const float* cg1_w  = (const float*)d_in[15];
  const float* cg1_b  = (const float*)d_in[16];
  const float* cg2_w  = (const float*)d_in[17];
  const float* cg2_b  = (const float*)d_in[18];
  const float* ff_w1  = (const float*)d_in[19];
  const float* ff_b1  = (const float*)d_in[20];
  const float* ff_w2  = (const float*)d_in[21];
  const float* ff_b2  = (const float*)d_in[22];
  const float* gamma1 = (const float*)d_in[23];
  const float* gamma2 = (const float*)d_in[24];
  float* out = (float*)d_out;
  float* ws  = (float*)d_ws;

  // -------- workspace layout (float units). Total 14,265,856 fl = 57.1 MB ---
  float* qkv     = ws + 0;            // 3,538,944 fp32; later h_bf + normed_bf
  float* Sbuf    = ws + 3538944;      // 5,308,416 fp32; later attn_out + xs_bf
  float* xs      = ws + 8847360;      // 1,179,648
  float* x2      = ws + 10027008;     // 1,179,648
  u16*   ofull_bf= (u16*)(ws + 11206656);   // 1,179,648 u16
  u16*   xa_bf   = (u16*)(ws + 11796480);   // 1,179,648 u16 ; later dwc_bf
  float* Qg      = ws + 12386304;     // 294,912
  float* KgT     = ws + 12681216;     // 294,912
  float* Vg      = ws + 12976128;     // 294,912
  float* Og      = ws + 13271040;     // 294,912
  float* sga     = ws + 13565952;     // 147,456
  float* scores  = ws + 13713408;     // 73,728
  float* sums    = ws + 13787136;     // 1,536
  float* vdiff   = ws + 13788672;     // 512
  float* denom   = ws + 13789184;     // 9,216
  float* extra   = ws + 13798400;     // 9,216
  float* sgate   = ws + 13807616;     // 4,608
  float* cgm     = ws + 13812224;     // 512
  float* cgate   = ws + 13812736;     // 512
  int*   idxb    = (int*)(ws + 13813248);   // 18,432 ints
  u16*   qkvBT   = (u16*)(ws + 13831680);   // 196,608 u16 [768][256]
  u16*   outBT   = (u16*)(ws + 13929984);   // 65,536  [256][256]
  u16*   pwBT    = (u16*)(ws + 13962752);   // 65,536  [256][256]
  u16*   ff1BT   = (u16*)(ws + 13995520);   // 262,144 [1024][256]
  u16*   ff2BT   = (u16*)(ws + 14126592);   // 262,144 [256][1024]
  u16*   sg1BT   = (u16*)(ws + 14257664);   // 16,384  [64][256] (rows 32+ zero)
  // aliases
  u16*   h_bf     = (u16*)qkv;              // 4,718,592 u16 @ [0, 2359296) fl
  u16*   normed_bf= (u16*)(ws + 2359296);   // 1,179,648 u16 @ [2359296, 2949120) fl
  float* attn_out = Sbuf;                   // 1,179,648 fl
  u16*   xs_bf    = (u16*)(ws + 4718592);   // 1,179,648 u16
  u16*   dwc_bf   = xa_bf;

  dim3 blk(256);
  hipMemsetAsync(sums, 0, 1536 * sizeof(float), stream);
  hipMemsetAsync(cgm, 0, 512 * sizeof(float), stream);

  // ---- weight prep (bf16 B^T) ----
  castT_kernel<<<dim3(768), blk, 0, stream>>>(qkv_w, qkvBT, 256, 768);
  castT_kernel<<<dim3(256), blk, 0, stream>>>(out_w, outBT, 256, 256);
  cast_kernel <<<dim3(256), blk, 0, stream>>>(pw_w, pwBT, 65536, 65536);
  castT_kernel<<<dim3(1024), blk, 0, stream>>>(ff_w1, ff1BT, 256, 1024);
  castT_kernel<<<dim3(1024), blk, 0, stream>>>(ff_w2, ff2BT, 1024, 256);
  cast_kernel <<<dim3(64),  blk, 0, stream>>>(sg1_w, sg1BT, 8192, 16384);

  // ---- attention branch ----
  ln_kernel<<<dim3(NROWS), blk, 0, stream>>>(x, xa_bf, ln1_g, ln1_b, N_PIX, 1);
  mgemm<0><<<dim3(12, 36), blk, 0, stream>>>(xa_bf, qkvBT, qkv, nullptr,
      256, 768, 768, nullptr, nullptr, nullptr);
  qkv_sums_kernel<<<dim3(BHN, 16), dim3(128), 0, stream>>>(qkv, sums);
  score_kernel<<<dim3(144), blk, 0, stream>>>(qkv, sums, scores, scores + BHN * N_PIX);
  topk_kernel<<<dim3(BHN, 2), blk, 0, stream>>>(scores, idxb);
  gather_kernel<<<dim3(72, BHN), blk, 0, stream>>>(qkv, idxb, Qg, KgT, Vg);
  vdiff_kernel<<<dim3(BHN), dim3(64), 0, stream>>>(Vg, sums, vdiff);
  ofill_kernel<<<dim3(NROWS), blk, 0, stream>>>(sums, ofull_bf);
  gemm_kernel<0><<<dim3(9, 9, BHN), blk, 0, stream>>>(Qg, KgT, Sbuf, KTOP, KTOP, 32,
      nullptr, nullptr, nullptr, (long)KTOP * 32, (long)32 * KTOP, (long)KTOP * KTOP);
  softprep_kernel<<<dim3(KTOP, BHN), dim3(64), 0, stream>>>(Sbuf, denom, extra);
  pv_kernel<<<dim3(72, BHN), blk, 0, stream>>>(Sbuf, Vg, vdiff, denom, extra, Og);
  scatter_kernel<<<dim3(72, BHN), blk, 0, stream>>>(Og, idxb, ofull_bf);
  mgemm<0><<<dim3(4, 36), blk, 0, stream>>>(ofull_bf, outBT, attn_out, nullptr,
      256, 256, 256, nullptr, nullptr, nullptr);

  // ---- conv branch ----
  dwconv_kernel<<<dim3(NROWS), blk, 0, stream>>>(x, dw_w, dw_b, dwc_bf);
  mgemm<2><<<dim3(4, 36), blk, 0, stream>>>(dwc_bf, pwBT, xs, xs_bf,
      256, 256, 256, pw_b, attn_out, nullptr);

  // ---- gates ----
  mgemm<3><<<dim3(1, 36), blk, 0, stream>>>(xs_bf, sg1BT, sga, nullptr,
      256, 32, 32, sg1_b, nullptr, nullptr);
  sg2_kernel<<<dim3(96), dim3(64), 0, stream>>>(sga, sg2_w, sg2_b, sgate);
  cgmean_kernel<<<dim3(36, 2), blk, 0, stream>>>(xs, cgm);
  cgmlp_kernel<<<dim3(2), blk, 0, stream>>>(cgm, cg1_w, cg1_b, cg2_w, cg2_b, cgate);
  x2_kernel<<<dim3(NROWS), blk, 0, stream>>>(x, xs, sgate, cgate, gamma1, x2);

  // ---- FFN ----
  ln_kernel<<<dim3(NROWS), blk, 0, stream>>>(x2, normed_bf, ln2_g, ln2_b, 1, 256);
  mgemm<4><<<dim3(16, 36), blk, 0, stream>>>(normed_bf, ff1BT, nullptr, h_bf,
      256, 1024, 1024, ff_b1, nullptr, nullptr);
  mgemm<5><<<dim3(4, 36), blk, 0, stream>>>(h_bf, ff2BT, out, nullptr,
      1024, 256, 256, ff_b2, x2, gamma2);
}

// Round 3
// 324.248 us; speedup vs baseline: 1.8949x; 1.4478x over previous
//
#include <hip/hip_runtime.h>
#include <math.h>

#define N_PIX 2304
#define CCH   256
#define BHN   16     // B * NHEAD
#define KTOP  576
#define NROWS 4608   // B * N_PIX

typedef unsigned short u16;
typedef __attribute__((ext_vector_type(8))) short short8v;   // 8 bf16
typedef __attribute__((ext_vector_type(4))) float floatx4;

__device__ __forceinline__ u16 f2b(float f) {
  unsigned int u = __float_as_uint(f);
  return (u16)((u + 0x7fffu + ((u >> 16) & 1u)) >> 16);      // RNE
}

__device__ __forceinline__ void async16(const void* g, void* l) {
  __builtin_amdgcn_global_load_lds(
      (const __attribute__((address_space(1))) unsigned int*)g,
      (__attribute__((address_space(3))) unsigned int*)l, 16, 0, 0);
}

// ============ ln1 tile-transpose: x NCHW -> xa_bf (LN'd NHWC bf16) + xnhwc fp32
// block = 32 pixels, 256 threads. Coalesced NCHW reads, coalesced NHWC writes.
__global__ __launch_bounds__(256) void ln1t_kernel(
    const float* __restrict__ x, u16* __restrict__ xa_bf, float* __restrict__ xnhwc,
    const float* __restrict__ g, const float* __restrict__ beta)
{
  __shared__ float tile[32 * 257];
  __shared__ float redS[8 * 32], redQ[8 * 32];
  __shared__ float mu_s[32], rs_s[32];
  int tid = threadIdx.x;
  int p0g = blockIdx.x * 32;                    // global row (b*N_PIX+pix)
  int bb = p0g / N_PIX; int p0 = p0g - bb * N_PIX;
  int px = tid & 31, csub = tid >> 5;
  float sacc = 0.f, qacc = 0.f;
#pragma unroll 4
  for (int it = 0; it < 32; ++it) {
    int c = it * 8 + csub;
    float v = x[((long)bb * 256 + c) * N_PIX + p0 + px];
    tile[px * 257 + c] = v;
    sacc += v; qacc += v * v;
  }
  redS[csub * 32 + px] = sacc; redQ[csub * 32 + px] = qacc;
  __syncthreads();
  if (tid < 32) {
    float s = 0.f, qq = 0.f;
#pragma unroll
    for (int j = 0; j < 8; ++j) { s += redS[j * 32 + tid]; qq += redQ[j * 32 + tid]; }
    float mu = s * (1.f / 256.f);
    float var = qq * (1.f / 256.f) - mu * mu;
    mu_s[tid] = mu; rs_s[tid] = rsqrtf(var + 1e-6f);
  }
  __syncthreads();
  float gv = g[tid], bv = beta[tid];
#pragma unroll 4
  for (int it = 0; it < 32; ++it) {
    float v = tile[it * 257 + tid];
    long orow = (long)(p0g + it) * 256 + tid;
    xnhwc[orow] = v;
    xa_bf[orow] = f2b((v - mu_s[it]) * rs_s[it] * gv + bv);
  }
}

// ============ LayerNorm NHWC fp32 -> bf16 (used for ln2) ============
__global__ __launch_bounds__(256) void ln_kernel(
    const float* __restrict__ in, u16* __restrict__ out,
    const float* __restrict__ g, const float* __restrict__ bvec)
{
  int r = blockIdx.x;
  const float* p = in + (long)r * CCH;
  int c = threadIdx.x;
  float v = p[c];
  __shared__ float red[256];
  red[c] = v; __syncthreads();
  for (int off = 128; off > 0; off >>= 1) { if (c < off) red[c] += red[c + off]; __syncthreads(); }
  float mu = red[0] * (1.f / 256.f);
  __syncthreads();
  float dv = v - mu;
  red[c] = dv * dv; __syncthreads();
  for (int off = 128; off > 0; off >>= 1) { if (c < off) red[c] += red[c + off]; __syncthreads(); }
  float var = red[0] * (1.f / 256.f);
  out[(long)r * CCH + c] = f2b(dv * rsqrtf(var + 1e-6f) * g[c] + bvec[c]);
}

// ============ all weight casts fused =================================
__global__ __launch_bounds__(256) void cast_all_kernel(
    const float* __restrict__ qkv_w, const float* __restrict__ out_w,
    const float* __restrict__ pw_w, const float* __restrict__ ff_w1,
    const float* __restrict__ ff_w2, const float* __restrict__ sg1_w,
    u16* __restrict__ qkvBT, u16* __restrict__ outBT, u16* __restrict__ pwBT,
    u16* __restrict__ ff1BT, u16* __restrict__ ff2BT, u16* __restrict__ sg1BT)
{
  int i = blockIdx.x * 256 + threadIdx.x;
  if (i < 196608) { int k = i / 768, n = i - k * 768; qkvBT[n * 256 + k] = f2b(qkv_w[i]); return; }
  i -= 196608;
  if (i < 65536) { int k = i >> 8, n = i & 255; outBT[n * 256 + k] = f2b(out_w[i]); return; }
  i -= 65536;
  if (i < 65536) { pwBT[i] = f2b(pw_w[i]); return; }
  i -= 65536;
  if (i < 262144) { int k = i >> 10, n = i & 1023; ff1BT[n * 256 + k] = f2b(ff_w1[i]); return; }
  i -= 262144;
  if (i < 262144) { int k = i & 1023, n = i >> 10; ff2BT[i] = f2b(ff_w2[k * 256 + n]); return; }
  i -= 262144;
  if (i < 16384) sg1BT[i] = (i < 8192) ? f2b(sg1_w[i]) : (u16)0;
}

// ============ bf16 MFMA GEMM: tile (MT*64)x64, BK=32 =================
// C[M,N] = A[M,K](bf16) @ BT[N,K]^T. 4 waves, wave owns MT*16 rows.
// EPI 0: C fp32 ; EPI 2: t=acc+bias+add -> C fp32 + C2 bf16
// EPI 3: silu(acc+bias) -> C fp32 cols<nvalid ; EPI 4: gelu(acc+bias) -> C2 bf16
// EPI 5: out NCHW = add(NHWC) + gamma*(acc+bias)
template<int MT, int EPI>
__global__ __launch_bounds__(256) void mgemm(
    const u16* __restrict__ A, const u16* __restrict__ BT,
    float* __restrict__ C, u16* __restrict__ C2,
    int K, int ldc, int nvalid,
    const float* __restrict__ bias, const float* __restrict__ add,
    const float* __restrict__ gamma)
{
  __shared__ u16 Als[MT * 64 * 32];
  __shared__ u16 Bls[64 * 32];
  int tid = threadIdx.x;
  int w = tid >> 6, lane = tid & 63;
  int row0 = blockIdx.y * (MT * 64), col0 = blockIdx.x * 64;
  const u16* Abase = A + (long)row0 * K;
  const u16* Bbase = BT + (long)col0 * K;
  int q = lane >> 4, l15 = lane & 15;

  floatx4 acc[MT][4];
#pragma unroll
  for (int mi = 0; mi < MT; ++mi)
#pragma unroll
    for (int ni = 0; ni < 4; ++ni) acc[mi][ni] = (floatx4)0.f;

  int ccB = w * 64 + lane;
  int rB = ccB >> 2, kB = (ccB & 3) << 3;

  for (int k0 = 0; k0 < K; k0 += 32) {
#pragma unroll
    for (int i = 0; i < MT; ++i) {
      int cc = w * (64 * MT) + i * 64 + lane;
      async16(Abase + (long)(cc >> 2) * K + k0 + ((cc & 3) << 3), &Als[cc * 8]);
    }
    async16(Bbase + (long)rB * K + k0 + kB, &Bls[ccB * 8]);
    __syncthreads();
    short8v a[MT];
#pragma unroll
    for (int mi = 0; mi < MT; ++mi)
      a[mi] = *(const short8v*)&Als[(w * (16 * MT) + mi * 16 + l15) * 32 + q * 8];
#pragma unroll
    for (int ni = 0; ni < 4; ++ni) {
      short8v b = *(const short8v*)&Bls[(ni * 16 + l15) * 32 + q * 8];
#pragma unroll
      for (int mi = 0; mi < MT; ++mi)
        acc[mi][ni] = __builtin_amdgcn_mfma_f32_16x16x32_bf16(a[mi], b, acc[mi][ni], 0, 0, 0);
    }
    __syncthreads();
  }

  float g2 = (EPI == 5) ? gamma[0] : 0.f;
#pragma unroll
  for (int mi = 0; mi < MT; ++mi) {
#pragma unroll
    for (int ni = 0; ni < 4; ++ni) {
      int c = col0 + ni * 16 + l15;
      int rbase = row0 + w * (16 * MT) + mi * 16 + q * 4;
#pragma unroll
      for (int reg = 0; reg < 4; ++reg) {
        long row = rbase + reg;
        float v = acc[mi][ni][reg];
        if (EPI == 0) {
          C[row * ldc + c] = v;
        } else if (EPI == 2) {
          float t = v + bias[c] + add[row * ldc + c];
          C[row * ldc + c] = t;
          C2[row * ldc + c] = f2b(t);
        } else if (EPI == 3) {
          if (c < nvalid) {
            float t = v + bias[c];
            C[row * (long)nvalid + c] = t / (1.f + expf(-t));
          }
        } else if (EPI == 4) {
          float t = v + bias[c];
          t = 0.5f * t * (1.f + erff(t * 0.70710678118654752f));
          C2[row * ldc + c] = f2b(t);
        } else if (EPI == 5) {
          float t = add[row * 256 + c] + g2 * (v + bias[c]);
          int bb = (int)(row / N_PIX); int p = (int)(row - (long)bb * N_PIX);
          C[((long)bb * 256 + c) * N_PIX + p] = t;
        }
      }
    }
  }
}

// ============ fp32 GEMM 64x64x16 (batched S = QK^T) ==================
__global__ __launch_bounds__(256) void gemm_kernel(
    const float* __restrict__ A, const float* __restrict__ B, float* __restrict__ C,
    int N, int K, long sA, long sB, long sC)
{
  __shared__ float As[16][68];
  __shared__ float Bs[16][68];
  int bz = blockIdx.z;
  A += sA * bz; B += sB * bz; C += sC * bz;
  int tid = threadIdx.x;
  int tx = tid & 15, ty = tid >> 4;
  int row0 = blockIdx.y * 64, col0 = blockIdx.x * 64;
  int ar = tid >> 2, ac = (tid & 3) << 2;
  int br = tid >> 4, bc = (tid & 15) << 2;
  float acc[4][4] = {{0.f}};
  const float* Aptr = A + (long)(row0 + ar) * K + ac;
  const float* Bptr = B + (long)br * N + col0 + bc;
  for (int k0 = 0; k0 < K; k0 += 16) {
    float4 av = *(const float4*)(Aptr);
    Aptr += 16;
    float4 bv = *(const float4*)(Bptr);
    Bptr += (long)16 * N;
    As[ac + 0][ar] = av.x; As[ac + 1][ar] = av.y; As[ac + 2][ar] = av.z; As[ac + 3][ar] = av.w;
    *(float4*)&Bs[br][bc] = bv;
    __syncthreads();
#pragma unroll
    for (int kk = 0; kk < 16; ++kk) {
      float4 a = *(const float4*)&As[kk][ty << 2];
      float4 b = *(const float4*)&Bs[kk][tx << 2];
      acc[0][0] += a.x * b.x; acc[0][1] += a.x * b.y; acc[0][2] += a.x * b.z; acc[0][3] += a.x * b.w;
      acc[1][0] += a.y * b.x; acc[1][1] += a.y * b.y; acc[1][2] += a.y * b.z; acc[1][3] += a.y * b.w;
      acc[2][0] += a.z * b.x; acc[2][1] += a.z * b.y; acc[2][2] += a.z * b.z; acc[2][3] += a.z * b.w;
      acc[3][0] += a.w * b.x; acc[3][1] += a.w * b.y; acc[3][2] += a.w * b.z; acc[3][3] += a.w * b.w;
    }
    __syncthreads();
  }
#pragma unroll
  for (int i = 0; i < 4; ++i) {
    long r = row0 + (ty << 2) + i;
#pragma unroll
    for (int j = 0; j < 4; ++j) C[r * N + col0 + (tx << 2) + j] = acc[i][j];
  }
}

// ============ q/k/v sums (coalesced, col-threaded) ===================
__global__ __launch_bounds__(256) void qkv_sums_kernel(
    const float* __restrict__ qkv, float* __restrict__ sums)
{
  int b = blockIdx.y / 3, third = blockIdx.y - (blockIdx.y / 3) * 3;
  int tid = threadIdx.x;
  int col = third * 256 + tid;
  int n0 = blockIdx.x * 144;
  const float* p = qkv + ((long)(b * N_PIX + n0)) * 768 + col;
  float s = 0.f;
  for (int t = 0; t < 144; ++t) { s += *p; p += 768; }
  int h = tid >> 5, d = tid & 31;
  atomicAdd(&sums[(b * 8 + h) * 96 + third * 32 + d], s);
}

// ============ rank-1 row/col scores ==================================
__global__ __launch_bounds__(256) void score_kernel(
    const float* __restrict__ qkv, const float* __restrict__ acc,
    float* __restrict__ rs, float* __restrict__ cs)
{
  int idx = blockIdx.x * 256 + threadIdx.x;
  if (idx >= BHN * N_PIX) return;
  int bh = idx / N_PIX, n = idx - bh * N_PIX;
  int b = bh >> 3, h = bh & 7;
  const float4* q4 = (const float4*)(qkv + ((long)(b * N_PIX + n)) * 768 + h * 32);
  const float4* k4 = q4 + 64;                  // +256 floats
  const float* qs = acc + bh * 96;
  const float* ks = acc + bh * 96 + 32;
  float r = 0.f, c = 0.f;
#pragma unroll
  for (int i = 0; i < 8; ++i) {
    float4 qv = q4[i], kv = k4[i];
    r += qv.x * ks[i * 4] + qv.y * ks[i * 4 + 1] + qv.z * ks[i * 4 + 2] + qv.w * ks[i * 4 + 3];
    c += kv.x * qs[i * 4] + kv.y * qs[i * 4 + 1] + kv.z * qs[i * 4 + 2] + kv.w * qs[i * 4 + 3];
  }
  rs[idx] = r; cs[idx] = c;
}

// ============ exact top-576: radix + ballot select (jax tie rule) =====
__global__ __launch_bounds__(256) void topk_kernel(
    const float* __restrict__ scores, int* __restrict__ out_idx)
{
  int bh = blockIdx.x, which = blockIdx.y;
  const float* s = scores + (long)(which * BHN + bh) * N_PIX;
  int* out = out_idx + (which * BHN + bh) * KTOP;
  __shared__ unsigned int u[N_PIX];
  __shared__ unsigned int hist[256];
  __shared__ unsigned int wtmp[4];
  __shared__ unsigned int sh_selbin, sh_selS;
  __shared__ unsigned int cnt_eq[4], cnt_sel[4];
  int tid = threadIdx.x;
  int wave = tid >> 6, lane = tid & 63;
  unsigned long long ltmask = (1ull << lane) - 1ull;
  for (int i = tid; i < N_PIX; i += 256) {
    unsigned int b = __float_as_uint(s[i]);
    u[i] = (b & 0x80000000u) ? ~b : (b | 0x80000000u);
  }
  __syncthreads();
  unsigned int prefix = 0u, kRem = KTOP;
  for (int pass = 0; pass < 4; ++pass) {
    int shift = 24 - pass * 8;
    hist[tid] = 0u;
    __syncthreads();
    unsigned int mask = (pass == 0) ? 0u : (0xFFFFFFFFu << (shift + 8));
    for (int i = tid; i < N_PIX; i += 256) {
      unsigned int v = u[i];
      if ((v & mask) == prefix) atomicAdd(&hist[(v >> shift) & 255u], 1u);
    }
    __syncthreads();
    // suffix-exclusive count over bins from the top: thread tid handles bin 255-tid
    int v = (int)hist[255 - tid];
    int xsc = v;
#pragma unroll
    for (int o = 1; o < 64; o <<= 1) { int y = __shfl_up(xsc, o); if (lane >= o) xsc += y; }
    if (lane == 63) wtmp[wave] = (unsigned int)xsc;
    __syncthreads();
    int wadd = 0;
    for (int ww = 0; ww < wave; ++ww) wadd += (int)wtmp[ww];
    unsigned int S = (unsigned int)(xsc + wadd - v);   // count in bins > (255-tid)
    if (S < kRem && S + (unsigned int)v >= kRem) { sh_selbin = (unsigned int)(255 - tid); sh_selS = S; }
    __syncthreads();
    prefix |= (sh_selbin << shift);
    kRem -= sh_selS;
    __syncthreads();
  }
  unsigned int T = prefix;
  unsigned int run_sel = 0u, run_eq = 0u;
  for (int c0 = 0; c0 < N_PIX; c0 += 256) {
    int i = c0 + tid;
    unsigned int v = u[i];
    bool isGt = v > T, isEq = (v == T);
    unsigned long long be = __ballot(isEq);
    unsigned int eqpre = (unsigned int)__popcll(be & ltmask);
    if (lane == 0) cnt_eq[wave] = (unsigned int)__popcll(be);
    __syncthreads();
    unsigned int eqoff = run_eq + eqpre;
    for (int ww = 0; ww < wave; ++ww) eqoff += cnt_eq[ww];
    bool selF = isGt || (isEq && eqoff < kRem);
    unsigned long long bs = __ballot(selF);
    unsigned int spre = (unsigned int)__popcll(bs & ltmask);
    if (lane == 0) cnt_sel[wave] = (unsigned int)__popcll(bs);
    __syncthreads();
    unsigned int soff = run_sel + spre;
    for (int ww = 0; ww < wave; ++ww) soff += cnt_sel[ww];
    if (selF) out[soff] = i;
    unsigned int te = 0, ts = 0;
#pragma unroll
    for (int ww = 0; ww < 4; ++ww) { te += cnt_eq[ww]; ts += cnt_sel[ww]; }
    run_eq += te; run_sel += ts;
    __syncthreads();
  }
}

// ============ gather kept rows/cols (+ kept-V column sums) ============
__global__ __launch_bounds__(256) void gather_kernel(
    const float* __restrict__ qkv, const int* __restrict__ idx,
    float* __restrict__ Qg, float* __restrict__ KgT, float* __restrict__ Vg,
    float* __restrict__ vneg)
{
  __shared__ float red[256];
  int bh = blockIdx.y;
  int tid = threadIdx.x;
  int r = blockIdx.x * 8 + (tid >> 5);
  int d = tid & 31;
  int b = bh >> 3, h = bh & 7;
  int rn = idx[bh * KTOP + r];
  int cn = idx[(BHN + bh) * KTOP + r];
  const float scale = 0.17677669529663687f;    // 1/sqrt(32)
  float vv = qkv[((long)(b * N_PIX + cn)) * 768 + 512 + h * 32 + d];
  Qg [((long)bh * KTOP + r) * 32 + d] = qkv[((long)(b * N_PIX + rn)) * 768 + h * 32 + d] * scale;
  KgT[((long)bh * 32 + d) * KTOP + r] = qkv[((long)(b * N_PIX + cn)) * 768 + 256 + h * 32 + d];
  Vg [((long)bh * KTOP + r) * 32 + d] = vv;
  red[tid] = vv;
  __syncthreads();
  if (tid < 32) {
    float s = 0.f;
#pragma unroll
    for (int j = 0; j < 8; ++j) s += red[j * 32 + tid];
    atomicAdd(&vneg[bh * 32 + tid], s);
  }
}

// ============ default rows: o = v_mean -> bf16 ========================
__global__ __launch_bounds__(256) void ofill_kernel(
    const float* __restrict__ sums, u16* __restrict__ ofull)
{
  int c = threadIdx.x;
  int b = blockIdx.x / N_PIX;
  int h = c >> 5, d = c & 31;
  ofull[(long)blockIdx.x * 256 + c] = f2b(sums[((b << 3) + h) * 96 + 64 + d] * (1.f / (float)N_PIX));
}

// ============ softmax + PV + scatter (one wave per kept row) ==========
__global__ __launch_bounds__(64) void softpv_kernel(
    const float* __restrict__ S, const float* __restrict__ Vg,
    const float* __restrict__ sums, const float* __restrict__ vneg,
    const int* __restrict__ idx, u16* __restrict__ ofull)
{
  __shared__ float P[KTOP];
  int bh = blockIdx.y, row = blockIdx.x;
  const float* p = S + ((long)bh * KTOP + row) * KTOP;
  int t = threadIdx.x;
  float m = -1e30f;
  for (int j = t; j < KTOP; j += 64) m = fmaxf(m, p[j]);
#pragma unroll
  for (int off = 32; off > 0; off >>= 1) m = fmaxf(m, __shfl_xor(m, off));
  m = fmaxf(m, 0.f);
  float s = 0.f;
  for (int j = t; j < KTOP; j += 64) { float e = expf(p[j] - m); P[j] = e; s += e; }
#pragma unroll
  for (int off = 32; off > 0; off >>= 1) s += __shfl_xor(s, off);
  float em = expf(-m);
  float denom = s + (float)(N_PIX - KTOP) * em;
  __syncthreads();
  int d = t & 31, half = t >> 5;
  const float* v = Vg + (long)bh * KTOP * 32 + d;
  float acc = 0.f;
  int j0 = half * (KTOP / 2);
#pragma unroll 4
  for (int j = j0; j < j0 + KTOP / 2; ++j) acc += P[j] * v[(long)j * 32];
  acc += __shfl_down(acc, 32);
  if (t < 32) {
    float vd = sums[bh * 96 + 64 + d] - vneg[bh * 32 + d];
    float oo = (acc + em * vd) / denom;
    int n = idx[bh * KTOP + row];
    int b = bh >> 3, h = bh & 7;
    ofull[((long)(b * N_PIX + n)) * 256 + h * 32 + d] = f2b(oo);
  }
}

// ============ depthwise 3x3 (NHWC fp32 in -> NHWC bf16 out) ===========
__global__ __launch_bounds__(256) void dwconv_kernel(
    const float* __restrict__ xnhwc, const float* __restrict__ w,
    const float* __restrict__ bias, u16* __restrict__ out_nhwc)
{
  int pix = blockIdx.x;
  int b = pix / N_PIX; int p = pix - b * N_PIX;
  int y = p / 48, xx = p - y * 48;
  int c = threadIdx.x;
  float acc = bias[c];
#pragma unroll
  for (int ky = 0; ky < 3; ++ky) {
    int yy = y + ky - 1; if (yy < 0 || yy >= 48) continue;
#pragma unroll
    for (int kx = 0; kx < 3; ++kx) {
      int xc = xx + kx - 1; if (xc < 0 || xc >= 48) continue;
      acc += w[c * 9 + ky * 3 + kx] * xnhwc[((long)(b * N_PIX + yy * 48 + xc)) * 256 + c];
    }
  }
  out_nhwc[(long)pix * 256 + c] = f2b(acc);
}

// ============ spatial gate 7x7 (32ch -> 1), 256 threads ===============
__global__ __launch_bounds__(256) void sg2_kernel(
    const float* __restrict__ sga, const float* __restrict__ w,
    const float* __restrict__ b1, float* __restrict__ sgate)
{
  __shared__ float ws[32 * 49];
  __shared__ float red[4 * 64];
  int by = blockIdx.x; int b = by / 48, y = by - b * 48;
  int t = threadIdx.x;
  for (int i = t; i < 32 * 49; i += 256) ws[i] = w[i];
  __syncthreads();
  int xx = t & 63, gg = t >> 6;          // xx<48 active, gg = 8-channel group
  float acc = 0.f;
  if (xx < 48) {
    for (int ky = 0; ky < 7; ++ky) {
      int yy = y + ky - 3; if (yy < 0 || yy >= 48) continue;
      for (int kx = 0; kx < 7; ++kx) {
        int xc = xx + kx - 3; if (xc < 0 || xc >= 48) continue;
        const float4* sp = (const float4*)(sga + ((long)(b * N_PIX + yy * 48 + xc)) * 32 + gg * 8);
        float4 v0 = sp[0], v1 = sp[1];
        int wb = gg * 8 * 49 + ky * 7 + kx;
        acc += ws[wb] * v0.x + ws[wb + 49] * v0.y + ws[wb + 98] * v0.z + ws[wb + 147] * v0.w;
        acc += ws[wb + 196] * v1.x + ws[wb + 245] * v1.y + ws[wb + 294] * v1.z + ws[wb + 343] * v1.w;
      }
    }
  }
  red[gg * 64 + xx] = acc;
  __syncthreads();
  if (t < 48) {
    float tot = b1[0] + red[t] + red[64 + t] + red[128 + t] + red[192 + t];
    sgate[b * N_PIX + y * 48 + t] = 1.f / (1.f + expf(-tot));
  }
}

// ============ channel gate ===========================================
__global__ __launch_bounds__(256) void cgmean_kernel(
    const float* __restrict__ xs, float* __restrict__ cgm)
{
  int chunk = blockIdx.x, b = blockIdx.y, c = threadIdx.x;
  const float* p = xs + ((long)(b * N_PIX + chunk * 64)) * 256 + c;
  float s = 0.f;
  for (int t = 0; t < 64; ++t) { s += *p; p += 256; }
  atomicAdd(&cgm[b * 256 + c], s);
}

__global__ __launch_bounds__(256) void cgmlp_kernel(
    const float* __restrict__ cgm, const float* __restrict__ w1, const float* __restrict__ b1,
    const float* __restrict__ w2, const float* __restrict__ b2, float* __restrict__ cgate)
{
  int b = blockIdx.x; int t = threadIdx.x;
  __shared__ float m[256];
  __shared__ float a[32];
  m[t] = cgm[b * 256 + t] * (1.f / (float)N_PIX);
  __syncthreads();
  if (t < 32) {
    float s = b1[t];
    for (int c = 0; c < 256; ++c) s += w1[t * 256 + c] * m[c];
    a[t] = s / (1.f + expf(-s));
  }
  __syncthreads();
  float s = b2[t];
#pragma unroll
  for (int g = 0; g < 32; ++g) s += w2[t * 32 + g] * a[g];
  cgate[b * 256 + t] = 1.f / (1.f + expf(-s));
}

// ============ x2 = x + gamma1*(xs*sg*cg) (NHWC, coalesced) ============
__global__ __launch_bounds__(256) void x2_kernel(
    const float* __restrict__ xnhwc, const float* __restrict__ xs,
    const float* __restrict__ sgate, const float* __restrict__ cgate,
    const float* __restrict__ gamma1, float* __restrict__ x2)
{
  int pix = blockIdx.x; int b = pix / N_PIX;
  int c = threadIdx.x;
  float xv = xnhwc[(long)pix * 256 + c];
  float v = xs[(long)pix * 256 + c] * sgate[pix] * cgate[b * 256 + c];
  x2[(long)pix * 256 + c] = xv + gamma1[0] * v;
}

// ======================================================================
extern "C" void kernel_launch(void* const* d_in, const int* in_sizes, int n_in,
                              void* d_out, int out_size, void* d_ws, size_t ws_size,
                              hipStream_t stream) {
  (void)in_sizes; (void)n_in; (void)out_size; (void)ws_size;
  const float* x      = (const float*)d_in[0];
  const float* qkv_w  = (const float*)d_in[1];
  const float* out_w  = (const float*)d_in[2];
  const float* ln1_g  = (const float*)d_in[3];
  const float* ln1_b  = (const float*)d_in[4];
  const float* ln2_g  = (const float*)d_in[5];
  const float* ln2_b  = (const float*)d_in[6];
  const float* dw_w   = (const float*)d_in[7];
  const float* dw_b   = (const float*)d_in[8];
  const float* pw_w   = (const float*)d_in[9];
  const float* pw_b   = (const float*)d_in[10];
  const float* sg1_w  = (const float*)d_in[11];
  const float* sg1_b  = (const float*)d_in[12];
  const float* sg2_w  = (const float*)d_in[13];
  const float* sg2_b  = (const float*)d_in[14];
  const float* cg1_w  = (const float*)d_in[15];
  const float* cg1_b  = (const float*)d_in[16];
  const float* cg2_w  = (const float*)d_in[17];
  const float* cg2_b  = (const float*)d_in[18];
  const float* ff_w1  = (const float*)d_in[19];
  const float* ff_b1  = (const float*)d_in[20];
  const float* ff_w2  = (const float*)d_in[21];
  const float* ff_b2  = (const float*)d_in[22];
  const float* gamma1 = (const float*)d_in[23];
  const float* gamma2 = (const float*)d_in[24];
  float* out = (float*)d_out;
  float* ws  = (float*)d_ws;

  // -------- workspace layout (float units), total 15,132,160 fl = 60.5 MB ---
  float* qkv     = ws + 0;                  // 3,538,944 fp32 [4608][768]
  float* Sbuf    = ws + 3538944;            // 5,308,416 fp32 S[16][576][576]
  float* xs      = ws + 8847360;            // 1,179,648
  float* x2      = ws + 10027008;           // 1,179,648
  u16*   ofull_bf= (u16*)(ws + 11206656);   // 589,824 fl
  u16*   xa_bf   = (u16*)(ws + 11796480);   // 589,824 fl ; later dwc_bf
  float* xnhwc   = ws + 12386304;           // 1,179,648
  float* Qg      = ws + 13565952;           // 294,912
  float* KgT     = ws + 13860864;           // 294,912
  float* Vg      = ws + 14155776;           // 294,912
  float* sga     = ws + 14450688;           // 147,456
  float* scores  = ws + 14598144;           // 73,728
  float* sums    = ws + 14671872;           // 1,536
  float* vneg    = ws + 14673408;           // 512
  float* cgm     = ws + 14673920;           // 512
  float* sgate   = ws + 14674432;           // 4,608
  float* cgate   = ws + 14679040;           // 512
  int*   idxb    = (int*)(ws + 14679552);   // 18,432 ints
  u16*   qkvBT   = (u16*)(ws + 14697984);   // 98,304 fl
  u16*   outBT   = (u16*)(ws + 14796288);   // 32,768 fl
  u16*   pwBT    = (u16*)(ws + 14829056);   // 32,768 fl
  u16*   ff1BT   = (u16*)(ws + 14861824);   // 131,072 fl
  u16*   ff2BT   = (u16*)(ws + 14992896);   // 131,072 fl
  u16*   sg1BT   = (u16*)(ws + 15123968);   // 8,192 fl
  // aliases
  u16*   h_bf     = (u16*)qkv;              // [0, 2359296) fl
  u16*   normed_bf= (u16*)(ws + 2359296);   // [2359296, 2949120) fl
  float* attn_out = Sbuf;                   // [Sbuf+0, +1179648) fl
  u16*   xs_bf    = (u16*)(ws + 4718592);   // [Sbuf+1179648, +1769472) fl
  u16*   dwc_bf   = xa_bf;

  dim3 blk(256);
  hipMemsetAsync(sums, 0, 2560 * sizeof(float), stream);   // sums+vneg+cgm

  cast_all_kernel<<<dim3(3392), blk, 0, stream>>>(qkv_w, out_w, pw_w, ff_w1, ff_w2, sg1_w,
      qkvBT, outBT, pwBT, ff1BT, ff2BT, sg1BT);

  // ---- attention branch ----
  ln1t_kernel<<<dim3(144), blk, 0, stream>>>(x, xa_bf, xnhwc, ln1_g, ln1_b);
  mgemm<2, 0><<<dim3(12, 36), blk, 0, stream>>>(xa_bf, qkvBT, qkv, nullptr,
      256, 768, 768, nullptr, nullptr, nullptr);
  qkv_sums_kernel<<<dim3(16, 6), blk, 0, stream>>>(qkv, sums);
  score_kernel<<<dim3(144), blk, 0, stream>>>(qkv, sums, scores, scores + BHN * N_PIX);
  topk_kernel<<<dim3(BHN, 2), blk, 0, stream>>>(scores, idxb);
  gather_kernel<<<dim3(72, BHN), blk, 0, stream>>>(qkv, idxb, Qg, KgT, Vg, vneg);
  ofill_kernel<<<dim3(NROWS), blk, 0, stream>>>(sums, ofull_bf);
  gemm_kernel<<<dim3(9, 9, BHN), blk, 0, stream>>>(Qg, KgT, Sbuf, KTOP, 32,
      (long)KTOP * 32, (long)32 * KTOP, (long)KTOP * KTOP);
  softpv_kernel<<<dim3(KTOP, BHN), dim3(64), 0, stream>>>(Sbuf, Vg, sums, vneg, idxb, ofull_bf);
  mgemm<1, 0><<<dim3(4, 72), blk, 0, stream>>>(ofull_bf, outBT, attn_out, nullptr,
      256, 256, 256, nullptr, nullptr, nullptr);

  // ---- conv branch ----
  dwconv_kernel<<<dim3(NROWS), blk, 0, stream>>>(xnhwc, dw_w, dw_b, dwc_bf);
  mgemm<1, 2><<<dim3(4, 72), blk, 0, stream>>>(dwc_bf, pwBT, xs, xs_bf,
      256, 256, 256, pw_b, attn_out, nullptr);

  // ---- gates ----
  mgemm<1, 3><<<dim3(1, 72), blk, 0, stream>>>(xs_bf, sg1BT, sga, nullptr,
      256, 32, 32, sg1_b, nullptr, nullptr);
  sg2_kernel<<<dim3(96), blk, 0, stream>>>(sga, sg2_w, sg2_b, sgate);
  cgmean_kernel<<<dim3(36, 2), blk, 0, stream>>>(xs, cgm);
  cgmlp_kernel<<<dim3(2), blk, 0, stream>>>(cgm, cg1_w, cg1_b, cg2_w, cg2_b, cgate);
  x2_kernel<<<dim3(NROWS), blk, 0, stream>>>(xnhwc, xs, sgate, cgate, gamma1, x2);

  // ---- FFN ----
  ln_kernel<<<dim3(NROWS), blk, 0, stream>>>(x2, normed_bf, ln2_g, ln2_b);
  mgemm<2, 4><<<dim3(16, 36), blk, 0, stream>>>(normed_bf, ff1BT, nullptr, h_bf,
      256, 1024, 1024, ff_b1, nullptr, nullptr);
  mgemm<1, 5><<<dim3(4, 72), blk, 0, stream>>>(h_bf, ff2BT, out, nullptr,
      1024, 256, 256, ff_b2, x2, gamma2);
}

// Round 6
// 281.303 us; speedup vs baseline: 2.1842x; 1.1527x over previous
//
#include <hip/hip_runtime.h>
#include <math.h>

#define N_PIX 2304
#define CCH   256
#define BHN   16     // B * NHEAD
#define KTOP  576
#define NROWS 4608   // B * N_PIX

typedef unsigned short u16;
typedef __attribute__((ext_vector_type(8))) short short8v;   // 8 bf16
typedef __attribute__((ext_vector_type(4))) float floatx4;

__device__ __forceinline__ u16 f2b(float f) {
  unsigned int u = __float_as_uint(f);
  return (u16)((u + 0x7fffu + ((u >> 16) & 1u)) >> 16);      // RNE
}

// NOTE (m104/m108): LDS dest of global_load_lds is wave-uniform base + lane*16.
// Every call site below must keep per-lane lds addr == base + lane*16.
__device__ __forceinline__ void async16(const void* g, void* l) {
  __builtin_amdgcn_global_load_lds(
      (const __attribute__((address_space(1))) unsigned int*)g,
      (__attribute__((address_space(3))) unsigned int*)l, 16, 0, 0);
}

// ============ ln1 tile-transpose: x NCHW -> xa_bf (LN'd NHWC bf16) + xnhwc fp32
__global__ __launch_bounds__(256) void ln1t_kernel(
    const float* __restrict__ x, u16* __restrict__ xa_bf, float* __restrict__ xnhwc,
    const float* __restrict__ g, const float* __restrict__ beta)
{
  __shared__ float tile[32 * 257];
  __shared__ float redS[8 * 32], redQ[8 * 32];
  __shared__ float mu_s[32], rs_s[32];
  int tid = threadIdx.x;
  int p0g = blockIdx.x * 32;
  int bb = p0g / N_PIX; int p0 = p0g - bb * N_PIX;
  int px = tid & 31, csub = tid >> 5;
  float sacc = 0.f, qacc = 0.f;
#pragma unroll 4
  for (int it = 0; it < 32; ++it) {
    int c = it * 8 + csub;
    float v = x[((long)bb * 256 + c) * N_PIX + p0 + px];
    tile[px * 257 + c] = v;
    sacc += v; qacc += v * v;
  }
  redS[csub * 32 + px] = sacc; redQ[csub * 32 + px] = qacc;
  __syncthreads();
  if (tid < 32) {
    float s = 0.f, qq = 0.f;
#pragma unroll
    for (int j = 0; j < 8; ++j) { s += redS[j * 32 + tid]; qq += redQ[j * 32 + tid]; }
    float mu = s * (1.f / 256.f);
    float var = qq * (1.f / 256.f) - mu * mu;
    mu_s[tid] = mu; rs_s[tid] = rsqrtf(var + 1e-6f);
  }
  __syncthreads();
  float gv = g[tid], bv = beta[tid];
#pragma unroll 4
  for (int it = 0; it < 32; ++it) {
    float v = tile[it * 257 + tid];
    long orow = (long)(p0g + it) * 256 + tid;
    xnhwc[orow] = v;
    xa_bf[orow] = f2b((v - mu_s[it]) * rs_s[it] * gv + bv);
  }
}

// ============ LayerNorm NHWC fp32 -> bf16 (ln2) ======================
__global__ __launch_bounds__(256) void ln_kernel(
    const float* __restrict__ in, u16* __restrict__ out,
    const float* __restrict__ g, const float* __restrict__ bvec)
{
  int r = blockIdx.x;
  const float* p = in + (long)r * CCH;
  int c = threadIdx.x;
  float v = p[c];
  __shared__ float red[256];
  red[c] = v; __syncthreads();
  for (int off = 128; off > 0; off >>= 1) { if (c < off) red[c] += red[c + off]; __syncthreads(); }
  float mu = red[0] * (1.f / 256.f);
  __syncthreads();
  float dv = v - mu;
  red[c] = dv * dv; __syncthreads();
  for (int off = 128; off > 0; off >>= 1) { if (c < off) red[c] += red[c + off]; __syncthreads(); }
  float var = red[0] * (1.f / 256.f);
  out[(long)r * CCH + c] = f2b(dv * rsqrtf(var + 1e-6f) * g[c] + bvec[c]);
}

// ============ all weight casts fused =================================
__global__ __launch_bounds__(256) void cast_all_kernel(
    const float* __restrict__ qkv_w, const float* __restrict__ out_w,
    const float* __restrict__ pw_w, const float* __restrict__ ff_w1,
    const float* __restrict__ ff_w2, const float* __restrict__ sg1_w,
    u16* __restrict__ qkvBT, u16* __restrict__ outBT, u16* __restrict__ pwBT,
    u16* __restrict__ ff1BT, u16* __restrict__ ff2BT, u16* __restrict__ sg1BT)
{
  int i = blockIdx.x * 256 + threadIdx.x;
  if (i < 196608) { int k = i / 768, n = i - k * 768; qkvBT[n * 256 + k] = f2b(qkv_w[i]); return; }
  i -= 196608;
  if (i < 65536) { int k = i >> 8, n = i & 255; outBT[n * 256 + k] = f2b(out_w[i]); return; }
  i -= 65536;
  if (i < 65536) { pwBT[i] = f2b(pw_w[i]); return; }
  i -= 65536;
  if (i < 262144) { int k = i >> 10, n = i & 1023; ff1BT[n * 256 + k] = f2b(ff_w1[i]); return; }
  i -= 262144;
  if (i < 262144) { int k = i & 1023, n = i >> 10; ff2BT[i] = f2b(ff_w2[k * 256 + n]); return; }
  i -= 262144;
  if (i < 16384) sg1BT[i] = (i < 8192) ? f2b(sg1_w[i]) : (u16)0;
}

// ============ bf16 MFMA GEMM: tile (MT*64)x64, BK=32 =================
template<int MT, int EPI>
__global__ __launch_bounds__(256) void mgemm(
    const u16* __restrict__ A, const u16* __restrict__ BT,
    float* __restrict__ C, u16* __restrict__ C2,
    int K, int ldc, int nvalid,
    const float* __restrict__ bias, const float* __restrict__ add,
    const float* __restrict__ gamma)
{
  __shared__ u16 Als[MT * 64 * 32];
  __shared__ u16 Bls[64 * 32];
  int tid = threadIdx.x;
  int w = tid >> 6, lane = tid & 63;
  int row0 = blockIdx.y * (MT * 64), col0 = blockIdx.x * 64;
  const u16* Abase = A + (long)row0 * K;
  const u16* Bbase = BT + (long)col0 * K;
  int q = lane >> 4, l15 = lane & 15;

  floatx4 acc[MT][4];
#pragma unroll
  for (int mi = 0; mi < MT; ++mi)
#pragma unroll
    for (int ni = 0; ni < 4; ++ni) acc[mi][ni] = (floatx4)0.f;

  int ccB = w * 64 + lane;
  int rB = ccB >> 2, kB = (ccB & 3) << 3;

  for (int k0 = 0; k0 < K; k0 += 32) {
#pragma unroll
    for (int i = 0; i < MT; ++i) {
      int cc = w * (64 * MT) + i * 64 + lane;
      async16(Abase + (long)(cc >> 2) * K + k0 + ((cc & 3) << 3), &Als[cc * 8]);
    }
    async16(Bbase + (long)rB * K + k0 + kB, &Bls[ccB * 8]);
    __syncthreads();
    short8v a[MT];
#pragma unroll
    for (int mi = 0; mi < MT; ++mi)
      a[mi] = *(const short8v*)&Als[(w * (16 * MT) + mi * 16 + l15) * 32 + q * 8];
#pragma unroll
    for (int ni = 0; ni < 4; ++ni) {
      short8v b = *(const short8v*)&Bls[(ni * 16 + l15) * 32 + q * 8];
#pragma unroll
      for (int mi = 0; mi < MT; ++mi)
        acc[mi][ni] = __builtin_amdgcn_mfma_f32_16x16x32_bf16(a[mi], b, acc[mi][ni], 0, 0, 0);
    }
    __syncthreads();
  }

  float g2 = (EPI == 5) ? gamma[0] : 0.f;
#pragma unroll
  for (int mi = 0; mi < MT; ++mi) {
#pragma unroll
    for (int ni = 0; ni < 4; ++ni) {
      int c = col0 + ni * 16 + l15;
      int rbase = row0 + w * (16 * MT) + mi * 16 + q * 4;
#pragma unroll
      for (int reg = 0; reg < 4; ++reg) {
        long row = rbase + reg;
        float v = acc[mi][ni][reg];
        if (EPI == 0) {
          C[row * ldc + c] = v;
        } else if (EPI == 2) {
          float t = v + bias[c] + add[row * ldc + c];
          C[row * ldc + c] = t;
          C2[row * ldc + c] = f2b(t);
        } else if (EPI == 3) {
          if (c < nvalid) {
            float t = v + bias[c];
            C[row * (long)nvalid + c] = t / (1.f + expf(-t));
          }
        } else if (EPI == 4) {
          float t = v + bias[c];
          t = 0.5f * t * (1.f + erff(t * 0.70710678118654752f));
          C2[row * ldc + c] = f2b(t);
        } else if (EPI == 5) {
          float t = add[row * 256 + c] + g2 * (v + bias[c]);
          int bb = (int)(row / N_PIX); int p = (int)(row - (long)bb * N_PIX);
          C[((long)bb * 256 + c) * N_PIX + p] = t;
        }
      }
    }
  }
}

// ============ batched bf16 MFMA S = Qg @ Kg^T (64x64 tile, K=32) ======
__global__ __launch_bounds__(256) void sgemm_kernel(
    const u16* __restrict__ Qg, const u16* __restrict__ Kg, float* __restrict__ S)
{
  __shared__ u16 Als[64 * 32];
  __shared__ u16 Bls[64 * 32];
  int bh = blockIdx.z;
  int tid = threadIdx.x;
  int w = tid >> 6, lane = tid & 63;
  int q = lane >> 4, l15 = lane & 15;
  int row0 = blockIdx.y * 64, col0 = blockIdx.x * 64;
  const u16* Ab = Qg + ((long)bh * KTOP + row0) * 32;
  const u16* Bb = Kg + ((long)bh * KTOP + col0) * 32;
  {
    int cc = tid;   // 256 chunks each; dest = base + lane*16 per wave
    async16(Ab + (long)(cc >> 2) * 32 + ((cc & 3) << 3), &Als[cc * 8]);
    async16(Bb + (long)(cc >> 2) * 32 + ((cc & 3) << 3), &Bls[cc * 8]);
  }
  __syncthreads();
  floatx4 acc[4];
#pragma unroll
  for (int ni = 0; ni < 4; ++ni) acc[ni] = (floatx4)0.f;
  short8v af = *(const short8v*)&Als[(w * 16 + l15) * 32 + q * 8];
#pragma unroll
  for (int ni = 0; ni < 4; ++ni) {
    short8v b = *(const short8v*)&Bls[(ni * 16 + l15) * 32 + q * 8];
    acc[ni] = __builtin_amdgcn_mfma_f32_16x16x32_bf16(af, b, acc[ni], 0, 0, 0);
  }
  long Sbase = (long)bh * KTOP * KTOP;
#pragma unroll
  for (int ni = 0; ni < 4; ++ni) {
    int c = col0 + ni * 16 + l15;
    int r0 = row0 + w * 16 + q * 4;
#pragma unroll
    for (int reg = 0; reg < 4; ++reg)
      S[Sbase + (long)(r0 + reg) * KTOP + c] = acc[ni][reg];
  }
}

// ============ q/k/v sums (coalesced, col-threaded) ===================
__global__ __launch_bounds__(256) void qkv_sums_kernel(
    const float* __restrict__ qkv, float* __restrict__ sums)
{
  int b = blockIdx.y / 3, third = blockIdx.y - (blockIdx.y / 3) * 3;
  int tid = threadIdx.x;
  int col = third * 256 + tid;
  int n0 = blockIdx.x * 144;
  const float* p = qkv + ((long)(b * N_PIX + n0)) * 768 + col;
  float s = 0.f;
  for (int t = 0; t < 144; ++t) { s += *p; p += 768; }
  int h = tid >> 5, d = tid & 31;
  atomicAdd(&sums[(b * 8 + h) * 96 + third * 32 + d], s);
}

// ============ rank-1 row/col scores ==================================
__global__ __launch_bounds__(256) void score_kernel(
    const float* __restrict__ qkv, const float* __restrict__ acc,
    float* __restrict__ rs, float* __restrict__ cs)
{
  int idx = blockIdx.x * 256 + threadIdx.x;
  if (idx >= BHN * N_PIX) return;
  int bh = idx / N_PIX, n = idx - bh * N_PIX;
  int b = bh >> 3, h = bh & 7;
  const float4* q4 = (const float4*)(qkv + ((long)(b * N_PIX + n)) * 768 + h * 32);
  const float4* k4 = q4 + 64;
  const float* qs = acc + bh * 96;
  const float* ks = acc + bh * 96 + 32;
  float r = 0.f, c = 0.f;
#pragma unroll
  for (int i = 0; i < 8; ++i) {
    float4 qv = q4[i], kv = k4[i];
    r += qv.x * ks[i * 4] + qv.y * ks[i * 4 + 1] + qv.z * ks[i * 4 + 2] + qv.w * ks[i * 4 + 3];
    c += kv.x * qs[i * 4] + kv.y * qs[i * 4 + 1] + kv.z * qs[i * 4 + 2] + kv.w * qs[i * 4 + 3];
  }
  rs[idx] = r; cs[idx] = c;
}

// ============ exact top-576: radix + ballot select (jax tie rule) =====
__global__ __launch_bounds__(256) void topk_kernel(
    const float* __restrict__ scores, int* __restrict__ out_idx)
{
  int bh = blockIdx.x, which = blockIdx.y;
  const float* s = scores + (long)(which * BHN + bh) * N_PIX;
  int* out = out_idx + (which * BHN + bh) * KTOP;
  __shared__ unsigned int u[N_PIX];
  __shared__ unsigned int hist[256];
  __shared__ unsigned int wtmp[4];
  __shared__ unsigned int sh_selbin, sh_selS;
  __shared__ unsigned int cnt_eq[4], cnt_sel[4];
  int tid = threadIdx.x;
  int wave = tid >> 6, lane = tid & 63;
  unsigned long long ltmask = (1ull << lane) - 1ull;
  for (int i = tid; i < N_PIX; i += 256) {
    unsigned int b = __float_as_uint(s[i]);
    u[i] = (b & 0x80000000u) ? ~b : (b | 0x80000000u);
  }
  __syncthreads();
  unsigned int prefix = 0u, kRem = KTOP;
  for (int pass = 0; pass < 4; ++pass) {
    int shift = 24 - pass * 8;
    hist[tid] = 0u;
    __syncthreads();
    unsigned int mask = (pass == 0) ? 0u : (0xFFFFFFFFu << (shift + 8));
    for (int i = tid; i < N_PIX; i += 256) {
      unsigned int v = u[i];
      if ((v & mask) == prefix) atomicAdd(&hist[(v >> shift) & 255u], 1u);
    }
    __syncthreads();
    int v = (int)hist[255 - tid];
    int xsc = v;
#pragma unroll
    for (int o = 1; o < 64; o <<= 1) { int y = __shfl_up(xsc, o); if (lane >= o) xsc += y; }
    if (lane == 63) wtmp[wave] = (unsigned int)xsc;
    __syncthreads();
    int wadd = 0;
    for (int ww = 0; ww < wave; ++ww) wadd += (int)wtmp[ww];
    unsigned int S = (unsigned int)(xsc + wadd - v);
    if (S < kRem && S + (unsigned int)v >= kRem) { sh_selbin = (unsigned int)(255 - tid); sh_selS = S; }
    __syncthreads();
    prefix |= (sh_selbin << shift);
    kRem -= sh_selS;
    __syncthreads();
  }
  unsigned int T = prefix;
  unsigned int run_sel = 0u, run_eq = 0u;
  for (int c0 = 0; c0 < N_PIX; c0 += 256) {
    int i = c0 + tid;
    unsigned int v = u[i];
    bool isGt = v > T, isEq = (v == T);
    unsigned long long be = __ballot(isEq);
    unsigned int eqpre = (unsigned int)__popcll(be & ltmask);
    if (lane == 0) cnt_eq[wave] = (unsigned int)__popcll(be);
    __syncthreads();
    unsigned int eqoff = run_eq + eqpre;
    for (int ww = 0; ww < wave; ++ww) eqoff += cnt_eq[ww];
    bool selF = isGt || (isEq && eqoff < kRem);
    unsigned long long bs = __ballot(selF);
    unsigned int spre = (unsigned int)__popcll(bs & ltmask);
    if (lane == 0) cnt_sel[wave] = (unsigned int)__popcll(bs);
    __syncthreads();
    unsigned int soff = run_sel + spre;
    for (int ww = 0; ww < wave; ++ww) soff += cnt_sel[ww];
    if (selF) out[soff] = i;
    unsigned int te = 0, ts = 0;
#pragma unroll
    for (int ww = 0; ww < 4; ++ww) { te += cnt_eq[ww]; ts += cnt_sel[ww]; }
    run_eq += te; run_sel += ts;
    __syncthreads();
  }
}

// ============ gather kept rows/cols -> bf16 (+ kept-V col sums) =======
__global__ __launch_bounds__(256) void gather_kernel(
    const float* __restrict__ qkv, const int* __restrict__ idx,
    u16* __restrict__ Qg, u16* __restrict__ Kg, u16* __restrict__ VgT,
    float* __restrict__ vneg)
{
  __shared__ float red[256];
  int bh = blockIdx.y;
  int tid = threadIdx.x;
  int r = blockIdx.x * 8 + (tid >> 5);
  int d = tid & 31;
  int b = bh >> 3, h = bh & 7;
  int rn = idx[bh * KTOP + r];
  int cn = idx[(BHN + bh) * KTOP + r];
  const float scale = 0.17677669529663687f;    // 1/sqrt(32)
  float vv = qkv[((long)(b * N_PIX + cn)) * 768 + 512 + h * 32 + d];
  Qg [((long)bh * KTOP + r) * 32 + d] = f2b(qkv[((long)(b * N_PIX + rn)) * 768 + h * 32 + d] * scale);
  Kg [((long)bh * KTOP + r) * 32 + d] = f2b(qkv[((long)(b * N_PIX + cn)) * 768 + 256 + h * 32 + d]);
  VgT[((long)bh * 32 + d) * 640 + r] = f2b(vv);
  red[tid] = vv;
  __syncthreads();
  if (tid < 32) {
    float s = 0.f;
#pragma unroll
    for (int j = 0; j < 8; ++j) s += red[j * 32 + tid];
    atomicAdd(&vneg[bh * 32 + tid], s);
  }
}

// ============ finish VgT: col 576 = vdiff, cols 577..639 = 0 ==========
__global__ __launch_bounds__(64) void vfin_kernel(
    const float* __restrict__ sums, const float* __restrict__ vneg, u16* __restrict__ VgT)
{
  int bh = blockIdx.x;
  int t = threadIdx.x;
  if (t < 32) {
    long base = ((long)bh * 32 + t) * 640;
    VgT[base + 576] = f2b(sums[bh * 96 + 64 + t] - vneg[bh * 32 + t]);
    for (int j = 577; j < 640; ++j) VgT[base + j] = 0;
  }
}

// ============ default rows: o = v_mean -> bf16 ========================
__global__ __launch_bounds__(256) void ofill_kernel(
    const float* __restrict__ sums, u16* __restrict__ ofull)
{
  int c = threadIdx.x;
  int b = blockIdx.x / N_PIX;
  int h = c >> 5, d = c & 31;
  ofull[(long)blockIdx.x * 256 + c] = f2b(sums[((b << 3) + h) * 96 + 64 + d] * (1.f / (float)N_PIX));
}

// ============ softmax prep: S fp32 -> P bf16 [576][640] ==============
// P[j<576] = exp(s-m)/denom ; P[576] = e^-m/denom ; P[577..639] = 0
__global__ __launch_bounds__(256) void softprep_kernel(
    const float* __restrict__ S, u16* __restrict__ P)
{
  int bh = blockIdx.y;
  int w = threadIdx.x >> 6, t = threadIdx.x & 63;
  int row = blockIdx.x * 4 + w;
  const float* p = S + ((long)bh * KTOP + row) * KTOP;
  float m = 0.f;                        // pruned cols contribute exp(0)
  float e[9];
#pragma unroll
  for (int i = 0; i < 9; ++i) { e[i] = p[t + i * 64]; m = fmaxf(m, e[i]); }
#pragma unroll
  for (int off = 32; off > 0; off >>= 1) m = fmaxf(m, __shfl_xor(m, off));
  float s = 0.f;
#pragma unroll
  for (int i = 0; i < 9; ++i) { e[i] = expf(e[i] - m); s += e[i]; }
#pragma unroll
  for (int off = 32; off > 0; off >>= 1) s += __shfl_xor(s, off);
  float em = expf(-m);
  float inv = 1.f / (s + (float)(N_PIX - KTOP) * em);
  u16* pr = P + ((long)bh * KTOP + row) * 640;
#pragma unroll
  for (int i = 0; i < 9; ++i) pr[t + i * 64] = f2b(e[i] * inv);
  pr[576 + t] = (t == 0) ? f2b(em * inv) : (u16)0;
}

// ============ PV: Og = P @ VgT^T via MFMA, scatter epilogue ==========
// grid (9 mtiles, 16 bh). 64 rows x 32 cols per block, K=640.
__global__ __launch_bounds__(256) void pvm_kernel(
    const u16* __restrict__ P, const u16* __restrict__ VgT,
    const int* __restrict__ idx, u16* __restrict__ ofull)
{
  __shared__ u16 Als[64 * 32];
  __shared__ u16 Bls[32 * 32];
  int bh = blockIdx.y;
  int tid = threadIdx.x;
  int w = tid >> 6, lane = tid & 63;
  int q = lane >> 4, l15 = lane & 15;
  int row0 = blockIdx.x * 64;
  const u16* Ab = P + ((long)bh * KTOP + row0) * 640;
  const u16* Bb = VgT + (long)bh * 32 * 640;
  floatx4 acc[2];
  acc[0] = (floatx4)0.f; acc[1] = (floatx4)0.f;
  for (int k0 = 0; k0 < 640; k0 += 32) {
    // A tile: 256 chunks, one per thread; dest = Als + tid*16B (= wave base + lane*16) OK
    {
      int cc = tid;
      async16(Ab + (long)(cc >> 2) * 640 + k0 + ((cc & 3) << 3), &Als[cc * 8]);
    }
    // B tile: 128 chunks on waves 0,1; dest = Bls + tid*16B (= wave base + lane*16) OK
    if (tid < 128) {
      int cb = tid;
      async16(Bb + (long)(cb >> 2) * 640 + k0 + ((cb & 3) << 3), &Bls[cb * 8]);
    }
    __syncthreads();
    short8v a = *(const short8v*)&Als[(w * 16 + l15) * 32 + q * 8];
#pragma unroll
    for (int ni = 0; ni < 2; ++ni) {
      short8v b = *(const short8v*)&Bls[(ni * 16 + l15) * 32 + q * 8];
      acc[ni] = __builtin_amdgcn_mfma_f32_16x16x32_bf16(a, b, acc[ni], 0, 0, 0);
    }
    __syncthreads();
  }
  int b = bh >> 3, h = bh & 7;
#pragma unroll
  for (int ni = 0; ni < 2; ++ni) {
    int d = ni * 16 + l15;
#pragma unroll
    for (int reg = 0; reg < 4; ++reg) {
      int r = row0 + w * 16 + q * 4 + reg;
      int n = idx[bh * KTOP + r];
      ofull[((long)(b * N_PIX + n)) * 256 + h * 32 + d] = f2b(acc[ni][reg]);
    }
  }
}

// ============ depthwise 3x3 (NHWC fp32 in -> NHWC bf16 out) ===========
__global__ __launch_bounds__(256) void dwconv_kernel(
    const float* __restrict__ xnhwc, const float* __restrict__ w,
    const float* __restrict__ bias, u16* __restrict__ out_nhwc)
{
  int pix = blockIdx.x;
  int b = pix / N_PIX; int p = pix - b * N_PIX;
  int y = p / 48, xx = p - y * 48;
  int c = threadIdx.x;
  float acc = bias[c];
#pragma unroll
  for (int ky = 0; ky < 3; ++ky) {
    int yy = y + ky - 1; if (yy < 0 || yy >= 48) continue;
#pragma unroll
    for (int kx = 0; kx < 3; ++kx) {
      int xc = xx + kx - 1; if (xc < 0 || xc >= 48) continue;
      acc += w[c * 9 + ky * 3 + kx] * xnhwc[((long)(b * N_PIX + yy * 48 + xc)) * 256 + c];
    }
  }
  out_nhwc[(long)pix * 256 + c] = f2b(acc);
}

// ============ spatial gate 7x7 (32ch -> 1), 256 threads ===============
__global__ __launch_bounds__(256) void sg2_kernel(
    const float* __restrict__ sga, const float* __restrict__ w,
    const float* __restrict__ b1, float* __restrict__ sgate)
{
  __shared__ float ws[32 * 49];
  __shared__ float red[4 * 64];
  int by = blockIdx.x; int b = by / 48, y = by - b * 48;
  int t = threadIdx.x;
  for (int i = t; i < 32 * 49; i += 256) ws[i] = w[i];
  __syncthreads();
  int xx = t & 63, gg = t >> 6;
  float acc = 0.f;
  if (xx < 48) {
    for (int ky = 0; ky < 7; ++ky) {
      int yy = y + ky - 3; if (yy < 0 || yy >= 48) continue;
      for (int kx = 0; kx < 7; ++kx) {
        int xc = xx + kx - 3; if (xc < 0 || xc >= 48) continue;
        const float4* sp = (const float4*)(sga + ((long)(b * N_PIX + yy * 48 + xc)) * 32 + gg * 8);
        float4 v0 = sp[0], v1 = sp[1];
        int wb = gg * 8 * 49 + ky * 7 + kx;
        acc += ws[wb] * v0.x + ws[wb + 49] * v0.y + ws[wb + 98] * v0.z + ws[wb + 147] * v0.w;
        acc += ws[wb + 196] * v1.x + ws[wb + 245] * v1.y + ws[wb + 294] * v1.z + ws[wb + 343] * v1.w;
      }
    }
  }
  red[gg * 64 + xx] = acc;
  __syncthreads();
  if (t < 48) {
    float tot = b1[0] + red[t] + red[64 + t] + red[128 + t] + red[192 + t];
    sgate[b * N_PIX + y * 48 + t] = 1.f / (1.f + expf(-tot));
  }
}

// ============ channel gate ===========================================
__global__ __launch_bounds__(256) void cgmean_kernel(
    const float* __restrict__ xs, float* __restrict__ cgm)
{
  int chunk = blockIdx.x, b = blockIdx.y, c = threadIdx.x;
  const float* p = xs + ((long)(b * N_PIX + chunk * 64)) * 256 + c;
  float s = 0.f;
  for (int t = 0; t < 64; ++t) { s += *p; p += 256; }
  atomicAdd(&cgm[b * 256 + c], s);
}

__global__ __launch_bounds__(256) void cgmlp_kernel(
    const float* __restrict__ cgm, const float* __restrict__ w1, const float* __restrict__ b1,
    const float* __restrict__ w2, const float* __restrict__ b2, float* __restrict__ cgate)
{
  int b = blockIdx.x; int t = threadIdx.x;
  __shared__ float m[256];
  __shared__ float a[32];
  m[t] = cgm[b * 256 + t] * (1.f / (float)N_PIX);
  __syncthreads();
  if (t < 32) {
    float s = b1[t];
    for (int c = 0; c < 256; ++c) s += w1[t * 256 + c] * m[c];
    a[t] = s / (1.f + expf(-s));
  }
  __syncthreads();
  float s = b2[t];
#pragma unroll
  for (int g = 0; g < 32; ++g) s += w2[t * 32 + g] * a[g];
  cgate[b * 256 + t] = 1.f / (1.f + expf(-s));
}

// ============ x2 = x + gamma1*(xs*sg*cg) (NHWC, coalesced) ============
__global__ __launch_bounds__(256) void x2_kernel(
    const float* __restrict__ xnhwc, const float* __restrict__ xs,
    const float* __restrict__ sgate, const float* __restrict__ cgate,
    const float* __restrict__ gamma1, float* __restrict__ x2)
{
  int pix = blockIdx.x; int b = pix / N_PIX;
  int c = threadIdx.x;
  float xv = xnhwc[(long)pix * 256 + c];
  float v = xs[(long)pix * 256 + c] * sgate[pix] * cgate[b * 256 + c];
  x2[(long)pix * 256 + c] = xv + gamma1[0] * v;
}

// ======================================================================
extern "C" void kernel_launch(void* const* d_in, const int* in_sizes, int n_in,
                              void* d_out, int out_size, void* d_ws, size_t ws_size,
                              hipStream_t stream) {
  (void)in_sizes; (void)n_in; (void)out_size; (void)ws_size;
  const float* x      = (const float*)d_in[0];
  const float* qkv_w  = (const float*)d_in[1];
  const float* out_w  = (const float*)d_in[2];
  const float* ln1_g  = (const float*)d_in[3];
  const float* ln1_b  = (const float*)d_in[4];
  const float* ln2_g  = (const float*)d_in[5];
  const float* ln2_b  = (const float*)d_in[6];
  const float* dw_w   = (const float*)d_in[7];
  const float* dw_b   = (const float*)d_in[8];
  const float* pw_w   = (const float*)d_in[9];
  const float* pw_b   = (const float*)d_in[10];
  const float* sg1_w  = (const float*)d_in[11];
  const float* sg1_b  = (const float*)d_in[12];
  const float* sg2_w  = (const float*)d_in[13];
  const float* sg2_b  = (const float*)d_in[14];
  const float* cg1_w  = (const float*)d_in[15];
  const float* cg1_b  = (const float*)d_in[16];
  const float* cg2_w  = (const float*)d_in[17];
  const float* cg2_b  = (const float*)d_in[18];
  const float* ff_w1  = (const float*)d_in[19];
  const float* ff_b1  = (const float*)d_in[20];
  const float* ff_w2  = (const float*)d_in[21];
  const float* ff_b2  = (const float*)d_in[22];
  const float* gamma1 = (const float*)d_in[23];
  const float* gamma2 = (const float*)d_in[24];
  float* out = (float*)d_out;
  float* ws  = (float*)d_ws;

  // -------- workspace layout (float units), total 14,706,176 fl = 58.8 MB ---
  float* qkv     = ws + 0;                  // 3,538,944 fp32; aliased by P / h_bf / normed_bf
  float* Sbuf    = ws + 3538944;            // 5,308,416 fp32 S[16][576][576]
  float* xs      = ws + 8847360;            // 1,179,648
  float* x2      = ws + 10027008;           // 1,179,648
  u16*   ofull_bf= (u16*)(ws + 11206656);   // 589,824 fl
  u16*   xa_bf   = (u16*)(ws + 11796480);   // 589,824 fl ; later dwc_bf
  float* xnhwc   = ws + 12386304;           // 1,179,648
  u16*   Qg_bf   = (u16*)(ws + 13565952);   // 147,456 fl
  u16*   Kg_bf   = (u16*)(ws + 13713408);   // 147,456 fl
  u16*   VgT     = (u16*)(ws + 13860864);   // 163,840 fl  [16][32][640]
  float* sga     = ws + 14024704;           // 147,456
  float* scores  = ws + 14172160;           // 73,728
  float* sums    = ws + 14245888;           // 1,536
  float* vneg    = ws + 14247424;           // 512
  float* cgm     = ws + 14247936;           // 512
  float* sgate   = ws + 14248448;           // 4,608
  float* cgate   = ws + 14253056;           // 512
  int*   idxb    = (int*)(ws + 14253568);   // 18,432 ints
  u16*   qkvBT   = (u16*)(ws + 14272000);   // 98,304 fl
  u16*   outBT   = (u16*)(ws + 14370304);   // 32,768 fl
  u16*   pwBT    = (u16*)(ws + 14403072);   // 32,768 fl
  u16*   ff1BT   = (u16*)(ws + 14435840);   // 131,072 fl
  u16*   ff2BT   = (u16*)(ws + 14566912);   // 131,072 fl
  u16*   sg1BT   = (u16*)(ws + 14697984);   // 8,192 fl -> end 14,706,176
  // time-multiplexed aliases of the qkv region (dead after gather):
  u16*   Pbuf     = (u16*)qkv;              // [0, 2,949,120) fl : P[16][576][640]
  u16*   h_bf     = (u16*)qkv;              // FFN phase
  u16*   normed_bf= (u16*)(ws + 2359296);
  float* attn_out = Sbuf;                   // S dead after softprep
  u16*   xs_bf    = (u16*)(ws + 4718592);
  u16*   dwc_bf   = xa_bf;

  dim3 blk(256);
  hipMemsetAsync(sums, 0, 2560 * sizeof(float), stream);   // sums+vneg+cgm

  cast_all_kernel<<<dim3(3392), blk, 0, stream>>>(qkv_w, out_w, pw_w, ff_w1, ff_w2, sg1_w,
      qkvBT, outBT, pwBT, ff1BT, ff2BT, sg1BT);

  // ---- attention branch ----
  ln1t_kernel<<<dim3(144), blk, 0, stream>>>(x, xa_bf, xnhwc, ln1_g, ln1_b);
  mgemm<2, 0><<<dim3(12, 36), blk, 0, stream>>>(xa_bf, qkvBT, qkv, nullptr,
      256, 768, 768, nullptr, nullptr, nullptr);
  qkv_sums_kernel<<<dim3(16, 6), blk, 0, stream>>>(qkv, sums);
  score_kernel<<<dim3(144), blk, 0, stream>>>(qkv, sums, scores, scores + BHN * N_PIX);
  topk_kernel<<<dim3(BHN, 2), blk, 0, stream>>>(scores, idxb);
  gather_kernel<<<dim3(72, BHN), blk, 0, stream>>>(qkv, idxb, Qg_bf, Kg_bf, VgT, vneg);
  vfin_kernel<<<dim3(BHN), dim3(64), 0, stream>>>(sums, vneg, VgT);
  ofill_kernel<<<dim3(NROWS), blk, 0, stream>>>(sums, ofull_bf);
  sgemm_kernel<<<dim3(9, 9, BHN), blk, 0, stream>>>(Qg_bf, Kg_bf, Sbuf);
  softprep_kernel<<<dim3(144, BHN), blk, 0, stream>>>(Sbuf, Pbuf);
  pvm_kernel<<<dim3(9, BHN), blk, 0, stream>>>(Pbuf, VgT, idxb, ofull_bf);
  mgemm<1, 0><<<dim3(4, 72), blk, 0, stream>>>(ofull_bf, outBT, attn_out, nullptr,
      256, 256, 256, nullptr, nullptr, nullptr);

  // ---- conv branch ----
  dwconv_kernel<<<dim3(NROWS), blk, 0, stream>>>(xnhwc, dw_w, dw_b, dwc_bf);
  mgemm<1, 2><<<dim3(4, 72), blk, 0, stream>>>(dwc_bf, pwBT, xs, xs_bf,
      256, 256, 256, pw_b, attn_out, nullptr);

  // ---- gates ----
  mgemm<1, 3><<<dim3(1, 72), blk, 0, stream>>>(xs_bf, sg1BT, sga, nullptr,
      256, 32, 32, sg1_b, nullptr, nullptr);
  sg2_kernel<<<dim3(96), blk, 0, stream>>>(sga, sg2_w, sg2_b, sgate);
  cgmean_kernel<<<dim3(36, 2), blk, 0, stream>>>(xs, cgm);
  cgmlp_kernel<<<dim3(2), blk, 0, stream>>>(cgm, cg1_w, cg1_b, cg2_w, cg2_b, cgate);
  x2_kernel<<<dim3(NROWS), blk, 0, stream>>>(xnhwc, xs, sgate, cgate, gamma1, x2);

  // ---- FFN ----
  ln_kernel<<<dim3(NROWS), blk, 0, stream>>>(x2, normed_bf, ln2_g, ln2_b);
  mgemm<2, 4><<<dim3(16, 36), blk, 0, stream>>>(normed_bf, ff1BT, nullptr, h_bf,
      256, 1024, 1024, ff_b1, nullptr, nullptr);
  mgemm<1, 5><<<dim3(4, 72), blk, 0, stream>>>(h_bf, ff2BT, out, nullptr,
      1024, 256, 256, ff_b2, x2, gamma2);
}

// Round 7
// 269.756 us; speedup vs baseline: 2.2777x; 1.0428x over previous
//
#include <hip/hip_runtime.h>
#include <math.h>

#define N_PIX 2304
#define CCH   256
#define BHN   16     // B * NHEAD
#define KTOP  576
#define NROWS 4608   // B * N_PIX

typedef unsigned short u16;
typedef __attribute__((ext_vector_type(8))) short short8v;   // 8 bf16
typedef __attribute__((ext_vector_type(4))) float floatx4;

__device__ __forceinline__ u16 f2b(float f) {
  unsigned int u = __float_as_uint(f);
  return (u16)((u + 0x7fffu + ((u >> 16) & 1u)) >> 16);      // RNE
}
__device__ __forceinline__ float b2f(u16 v) {
  return __uint_as_float(((unsigned int)v) << 16);
}

// NOTE (m104/m108): LDS dest of global_load_lds is wave-uniform base + lane*16.
__device__ __forceinline__ void async16(const void* g, void* l) {
  __builtin_amdgcn_global_load_lds(
      (const __attribute__((address_space(1))) unsigned int*)g,
      (__attribute__((address_space(3))) unsigned int*)l, 16, 0, 0);
}

// ============ ln1 tile-transpose: x NCHW -> xa_bf (LN'd NHWC bf16) + xnhwc fp32
__global__ __launch_bounds__(256) void ln1t_kernel(
    const float* __restrict__ x, u16* __restrict__ xa_bf, float* __restrict__ xnhwc,
    const float* __restrict__ g, const float* __restrict__ beta)
{
  __shared__ float tile[32 * 257];
  __shared__ float redS[8 * 32], redQ[8 * 32];
  __shared__ float mu_s[32], rs_s[32];
  int tid = threadIdx.x;
  int p0g = blockIdx.x * 32;
  int bb = p0g / N_PIX; int p0 = p0g - bb * N_PIX;
  int px = tid & 31, csub = tid >> 5;
  float sacc = 0.f, qacc = 0.f;
#pragma unroll 4
  for (int it = 0; it < 32; ++it) {
    int c = it * 8 + csub;
    float v = x[((long)bb * 256 + c) * N_PIX + p0 + px];
    tile[px * 257 + c] = v;
    sacc += v; qacc += v * v;
  }
  redS[csub * 32 + px] = sacc; redQ[csub * 32 + px] = qacc;
  __syncthreads();
  if (tid < 32) {
    float s = 0.f, qq = 0.f;
#pragma unroll
    for (int j = 0; j < 8; ++j) { s += redS[j * 32 + tid]; qq += redQ[j * 32 + tid]; }
    float mu = s * (1.f / 256.f);
    float var = qq * (1.f / 256.f) - mu * mu;
    mu_s[tid] = mu; rs_s[tid] = rsqrtf(var + 1e-6f);
  }
  __syncthreads();
  float gv = g[tid], bv = beta[tid];
#pragma unroll 4
  for (int it = 0; it < 32; ++it) {
    float v = tile[it * 257 + tid];
    long orow = (long)(p0g + it) * 256 + tid;
    xnhwc[orow] = v;
    xa_bf[orow] = f2b((v - mu_s[it]) * rs_s[it] * gv + bv);
  }
}

// ============ all weight casts fused =================================
__global__ __launch_bounds__(256) void cast_all_kernel(
    const float* __restrict__ qkv_w, const float* __restrict__ out_w,
    const float* __restrict__ pw_w, const float* __restrict__ ff_w1,
    const float* __restrict__ ff_w2, const float* __restrict__ sg1_w,
    u16* __restrict__ qkvBT, u16* __restrict__ outBT, u16* __restrict__ pwBT,
    u16* __restrict__ ff1BT, u16* __restrict__ ff2BT, u16* __restrict__ sg1BT)
{
  int i = blockIdx.x * 256 + threadIdx.x;
  if (i < 196608) { int k = i / 768, n = i - k * 768; qkvBT[n * 256 + k] = f2b(qkv_w[i]); return; }
  i -= 196608;
  if (i < 65536) { int k = i >> 8, n = i & 255; outBT[n * 256 + k] = f2b(out_w[i]); return; }
  i -= 65536;
  if (i < 65536) { pwBT[i] = f2b(pw_w[i]); return; }
  i -= 65536;
  if (i < 262144) { int k = i >> 10, n = i & 1023; ff1BT[n * 256 + k] = f2b(ff_w1[i]); return; }
  i -= 262144;
  if (i < 262144) { int k = i & 1023, n = i >> 10; ff2BT[i] = f2b(ff_w2[k * 256 + n]); return; }
  i -= 262144;
  if (i < 16384) sg1BT[i] = (i < 8192) ? f2b(sg1_w[i]) : (u16)0;
}

// ============ bf16 MFMA GEMM: tile (MT*64)x64, BK=32 =================
// EPI 0: C fp32 = acc
// EPI 3: silu(acc+bias) -> C fp32, cols < nvalid
// EPI 4: gelu(acc+bias) -> C2 bf16
// EPI 5: out NCHW = add(NHWC fp32) + gamma*(acc+bias)
// EPI 6: t = acc+bias+add -> C2 bf16 only
// CS=1: atomicAdd per-column sums of epilogue value into cs_out[b*cs_ld + c]
template<int MT, int EPI, int CS>
__global__ __launch_bounds__(256) void mgemm(
    const u16* __restrict__ A, const u16* __restrict__ BT,
    float* __restrict__ C, u16* __restrict__ C2,
    int K, int ldc, int nvalid,
    const float* __restrict__ bias, const float* __restrict__ add,
    const float* __restrict__ gamma,
    float* __restrict__ cs_out, int cs_ld)
{
  __shared__ u16 Als[MT * 64 * 32];
  __shared__ u16 Bls[64 * 32];
  int tid = threadIdx.x;
  int w = tid >> 6, lane = tid & 63;
  int row0 = blockIdx.y * (MT * 64), col0 = blockIdx.x * 64;
  const u16* Abase = A + (long)row0 * K;
  const u16* Bbase = BT + (long)col0 * K;
  int q = lane >> 4, l15 = lane & 15;

  floatx4 acc[MT][4];
#pragma unroll
  for (int mi = 0; mi < MT; ++mi)
#pragma unroll
    for (int ni = 0; ni < 4; ++ni) acc[mi][ni] = (floatx4)0.f;

  int ccB = w * 64 + lane;
  int rB = ccB >> 2, kB = (ccB & 3) << 3;

  for (int k0 = 0; k0 < K; k0 += 32) {
#pragma unroll
    for (int i = 0; i < MT; ++i) {
      int cc = w * (64 * MT) + i * 64 + lane;
      async16(Abase + (long)(cc >> 2) * K + k0 + ((cc & 3) << 3), &Als[cc * 8]);
    }
    async16(Bbase + (long)rB * K + k0 + kB, &Bls[ccB * 8]);
    __syncthreads();
    short8v a[MT];
#pragma unroll
    for (int mi = 0; mi < MT; ++mi)
      a[mi] = *(const short8v*)&Als[(w * (16 * MT) + mi * 16 + l15) * 32 + q * 8];
#pragma unroll
    for (int ni = 0; ni < 4; ++ni) {
      short8v b = *(const short8v*)&Bls[(ni * 16 + l15) * 32 + q * 8];
#pragma unroll
      for (int mi = 0; mi < MT; ++mi)
        acc[mi][ni] = __builtin_amdgcn_mfma_f32_16x16x32_bf16(a[mi], b, acc[mi][ni], 0, 0, 0);
    }
    __syncthreads();
  }

  float g2 = (EPI == 5) ? gamma[0] : 0.f;
  float cp[4] = {0.f, 0.f, 0.f, 0.f};
#pragma unroll
  for (int mi = 0; mi < MT; ++mi) {
#pragma unroll
    for (int ni = 0; ni < 4; ++ni) {
      int c = col0 + ni * 16 + l15;
      int rbase = row0 + w * (16 * MT) + mi * 16 + q * 4;
#pragma unroll
      for (int reg = 0; reg < 4; ++reg) {
        long row = rbase + reg;
        float v = acc[mi][ni][reg];
        if (EPI == 0) {
          C[row * ldc + c] = v;
          if (CS) cp[ni] += v;
        } else if (EPI == 3) {
          if (c < nvalid) {
            float t = v + bias[c];
            C[row * (long)nvalid + c] = t / (1.f + expf(-t));
          }
        } else if (EPI == 4) {
          float t = v + bias[c];
          t = 0.5f * t * (1.f + erff(t * 0.70710678118654752f));
          C2[row * ldc + c] = f2b(t);
        } else if (EPI == 5) {
          float t = add[row * 256 + c] + g2 * (v + bias[c]);
          int bb = (int)(row / N_PIX); int p = (int)(row - (long)bb * N_PIX);
          C[((long)bb * 256 + c) * N_PIX + p] = t;
        } else if (EPI == 6) {
          float t = v + bias[c] + add[row * ldc + c];
          C2[row * ldc + c] = f2b(t);
          if (CS) cp[ni] += t;
        }
      }
    }
  }
  if (CS) {
    int bb = (row0 >= N_PIX) ? 1 : 0;   // M=4608 grids only; batch boundary block-aligned
#pragma unroll
    for (int ni = 0; ni < 4; ++ni) {
      float r = cp[ni];
      r += __shfl_xor(r, 16);
      r += __shfl_xor(r, 32);
      if (lane < 16) atomicAdd(&cs_out[bb * cs_ld + col0 + ni * 16 + l15], r);
    }
  }
}

// ============ fused score + exact top-576 (radix + ballot, jax ties) ==
__global__ __launch_bounds__(256) void topkscore_kernel(
    const float* __restrict__ qkv, const float* __restrict__ csum, int* __restrict__ out_idx)
{
  int bh = blockIdx.x, which = blockIdx.y;
  int b = bh >> 3, h = bh & 7;
  int* out = out_idx + (which * BHN + bh) * KTOP;
  __shared__ unsigned int u[N_PIX];
  __shared__ unsigned int hist[256];
  __shared__ unsigned int wtmp[4];
  __shared__ unsigned int sh_selbin, sh_selS;
  __shared__ unsigned int cnt_eq[4], cnt_sel[4];
  __shared__ float svl[32];
  int tid = threadIdx.x;
  int wave = tid >> 6, lane = tid & 63;
  unsigned long long ltmask = (1ull << lane) - 1ull;
  // sum vector: rows use ksum (q·ksum), cols use qsum (k·qsum)
  if (tid < 32) svl[tid] = csum[b * 768 + (which ? 0 : 256) + h * 32 + tid];
  __syncthreads();
  int off = (which ? 256 : 0) + h * 32;
  for (int i = tid; i < N_PIX; i += 256) {
    const float4* p4 = (const float4*)(qkv + ((long)(b * N_PIX + i)) * 768 + off);
    float sc = 0.f;
#pragma unroll
    for (int j = 0; j < 8; ++j) {
      float4 v = p4[j];
      sc += v.x * svl[j * 4] + v.y * svl[j * 4 + 1] + v.z * svl[j * 4 + 2] + v.w * svl[j * 4 + 3];
    }
    unsigned int bu = __float_as_uint(sc);
    u[i] = (bu & 0x80000000u) ? ~bu : (bu | 0x80000000u);
  }
  __syncthreads();
  unsigned int prefix = 0u, kRem = KTOP;
  for (int pass = 0; pass < 4; ++pass) {
    int shift = 24 - pass * 8;
    hist[tid] = 0u;
    __syncthreads();
    unsigned int mask = (pass == 0) ? 0u : (0xFFFFFFFFu << (shift + 8));
    for (int i = tid; i < N_PIX; i += 256) {
      unsigned int v = u[i];
      if ((v & mask) == prefix) atomicAdd(&hist[(v >> shift) & 255u], 1u);
    }
    __syncthreads();
    int v = (int)hist[255 - tid];
    int xsc = v;
#pragma unroll
    for (int o = 1; o < 64; o <<= 1) { int y = __shfl_up(xsc, o); if (lane >= o) xsc += y; }
    if (lane == 63) wtmp[wave] = (unsigned int)xsc;
    __syncthreads();
    int wadd = 0;
    for (int ww = 0; ww < wave; ++ww) wadd += (int)wtmp[ww];
    unsigned int S = (unsigned int)(xsc + wadd - v);
    if (S < kRem && S + (unsigned int)v >= kRem) { sh_selbin = (unsigned int)(255 - tid); sh_selS = S; }
    __syncthreads();
    prefix |= (sh_selbin << shift);
    kRem -= sh_selS;
    __syncthreads();
  }
  unsigned int T = prefix;
  unsigned int run_sel = 0u, run_eq = 0u;
  for (int c0 = 0; c0 < N_PIX; c0 += 256) {
    int i = c0 + tid;
    unsigned int v = u[i];
    bool isGt = v > T, isEq = (v == T);
    unsigned long long be = __ballot(isEq);
    unsigned int eqpre = (unsigned int)__popcll(be & ltmask);
    if (lane == 0) cnt_eq[wave] = (unsigned int)__popcll(be);
    __syncthreads();
    unsigned int eqoff = run_eq + eqpre;
    for (int ww = 0; ww < wave; ++ww) eqoff += cnt_eq[ww];
    bool selF = isGt || (isEq && eqoff < kRem);
    unsigned long long bs = __ballot(selF);
    unsigned int spre = (unsigned int)__popcll(bs & ltmask);
    if (lane == 0) cnt_sel[wave] = (unsigned int)__popcll(bs);
    __syncthreads();
    unsigned int soff = run_sel + spre;
    for (int ww = 0; ww < wave; ++ww) soff += cnt_sel[ww];
    if (selF) out[soff] = i;
    unsigned int te = 0, ts = 0;
#pragma unroll
    for (int ww = 0; ww < 4; ++ww) { te += cnt_eq[ww]; ts += cnt_sel[ww]; }
    run_eq += te; run_sel += ts;
    __syncthreads();
  }
}

// ============ gather kept rows/cols -> bf16 (+ kept-V col sums) =======
// VgT layout: [bh][32][584] (stride 584, pad cols 576.. never read)
__global__ __launch_bounds__(256) void gather_kernel(
    const float* __restrict__ qkv, const int* __restrict__ idx,
    u16* __restrict__ Qg, u16* __restrict__ Kg, u16* __restrict__ VgT,
    float* __restrict__ vneg)
{
  __shared__ float red[256];
  int bh = blockIdx.y;
  int tid = threadIdx.x;
  int r = blockIdx.x * 8 + (tid >> 5);
  int d = tid & 31;
  int b = bh >> 3, h = bh & 7;
  int rn = idx[bh * KTOP + r];
  int cn = idx[(BHN + bh) * KTOP + r];
  const float scale = 0.17677669529663687f;    // 1/sqrt(32)
  float vv = qkv[((long)(b * N_PIX + cn)) * 768 + 512 + h * 32 + d];
  Qg [((long)bh * KTOP + r) * 32 + d] = f2b(qkv[((long)(b * N_PIX + rn)) * 768 + h * 32 + d] * scale);
  Kg [((long)bh * KTOP + r) * 32 + d] = f2b(qkv[((long)(b * N_PIX + cn)) * 768 + 256 + h * 32 + d]);
  VgT[((long)bh * 32 + d) * 584 + r] = f2b(vv);
  red[tid] = vv;
  __syncthreads();
  if (tid < 32) {
    float s = 0.f;
#pragma unroll
    for (int j = 0; j < 8; ++j) s += red[j * 32 + tid];
    atomicAdd(&vneg[bh * 32 + tid], s);
  }
}

// ============ default rows: o = v_mean -> bf16 ========================
__global__ __launch_bounds__(256) void ofill_kernel(
    const float* __restrict__ csum, u16* __restrict__ ofull)
{
  int c = threadIdx.x;
  int b = blockIdx.x / N_PIX;
  ofull[(long)blockIdx.x * 256 + c] = f2b(csum[b * 768 + 512 + c] * (1.f / (float)N_PIX));
}

// ============ fused attention core: S=QK^T, softmax, E@V^T, scatter ===
// grid (18, 16): 32 q-rows per block. Phase 1: wave w covers cols w*144..+144.
// Phase 2: wave w -> (m-tile w&1, n-tile w>>1), K=576.
__global__ __launch_bounds__(256) void attn_kernel(
    const u16* __restrict__ Qg, const u16* __restrict__ Kg, const u16* __restrict__ VgT,
    const float* __restrict__ csum, const float* __restrict__ vneg,
    const int* __restrict__ idx, u16* __restrict__ ofull)
{
  __shared__ u16 Pls[32 * 584];          // E (unnormalized exp), bf16
  __shared__ float wmax[4 * 32], wsum[4 * 32];
  __shared__ float emv_s[32], invd_s[32], vdif_s[32];
  int bh = blockIdx.y;
  int row0 = blockIdx.x * 32;
  int tid = threadIdx.x;
  int w = tid >> 6, lane = tid & 63;
  int q = lane >> 4, l15 = lane & 15;
  int b = bh >> 3, h = bh & 7;
  if (tid < 32) vdif_s[tid] = csum[b * 768 + 512 + h * 32 + tid] - vneg[bh * 32 + tid];
  const u16* Qb = Qg + (long)bh * KTOP * 32;
  const u16* Kb = Kg + (long)bh * KTOP * 32;
  // ---- phase 1: S = Q.K^T (rows row0..row0+32, cols w*144..+144) ----
  short8v af[2];
#pragma unroll
  for (int mi = 0; mi < 2; ++mi)
    af[mi] = *(const short8v*)(Qb + ((long)(row0 + mi * 16 + l15)) * 32 + q * 8);
  floatx4 sacc[2][9];
#pragma unroll
  for (int mi = 0; mi < 2; ++mi)
#pragma unroll
    for (int ni = 0; ni < 9; ++ni) sacc[mi][ni] = (floatx4)0.f;
#pragma unroll
  for (int ni = 0; ni < 9; ++ni) {
    int n = w * 144 + ni * 16 + l15;
    short8v bf = *(const short8v*)(Kb + (long)n * 32 + q * 8);
#pragma unroll
    for (int mi = 0; mi < 2; ++mi)
      sacc[mi][ni] = __builtin_amdgcn_mfma_f32_16x16x32_bf16(af[mi], bf, sacc[mi][ni], 0, 0, 0);
  }
  // per-row max within wave (C layout: row = mi*16 + q*4 + reg, col = ni*16 + l15)
#pragma unroll
  for (int mi = 0; mi < 2; ++mi)
#pragma unroll
    for (int reg = 0; reg < 4; ++reg) {
      float m = sacc[mi][0][reg];
#pragma unroll
      for (int ni = 1; ni < 9; ++ni) m = fmaxf(m, sacc[mi][ni][reg]);
#pragma unroll
      for (int o = 1; o < 16; o <<= 1) m = fmaxf(m, __shfl_xor(m, o));
      if (l15 == 0) wmax[w * 32 + mi * 16 + q * 4 + reg] = m;
    }
  __syncthreads();
  // global row max (incl. 0 for pruned cols), exp, E -> LDS, partial sums
#pragma unroll
  for (int mi = 0; mi < 2; ++mi)
#pragma unroll
    for (int reg = 0; reg < 4; ++reg) {
      int r = mi * 16 + q * 4 + reg;
      float gm = fmaxf(fmaxf(fmaxf(wmax[r], wmax[32 + r]), fmaxf(wmax[64 + r], wmax[96 + r])), 0.f);
      float s = 0.f;
#pragma unroll
      for (int ni = 0; ni < 9; ++ni) {
        float e = expf(sacc[mi][ni][reg] - gm);
        s += e;
        Pls[r * 584 + w * 144 + ni * 16 + l15] = f2b(e);
      }
#pragma unroll
      for (int o = 1; o < 16; o <<= 1) s += __shfl_xor(s, o);
      if (l15 == 0) wsum[w * 32 + r] = s;
    }
  __syncthreads();
  if (tid < 32) {
    float gm = fmaxf(fmaxf(fmaxf(wmax[tid], wmax[32 + tid]), fmaxf(wmax[64 + tid], wmax[96 + tid])), 0.f);
    float s = wsum[tid] + wsum[32 + tid] + wsum[64 + tid] + wsum[96 + tid];
    float em = expf(-gm);
    float inv = 1.f / (s + (float)(N_PIX - KTOP) * em);
    invd_s[tid] = inv;
    emv_s[tid] = em * inv;
  }
  __syncthreads();
  // ---- phase 2: O = E @ V^T  (wave -> m-tile mw, n-tile nw) ----
  int mw = w & 1, nw = w >> 1;
  const u16* Vb = VgT + (long)bh * 32 * 584;
  floatx4 acc = (floatx4)0.f;
#pragma unroll
  for (int kt = 0; kt < 18; ++kt) {
    int k0 = kt * 32;
    short8v a = *(const short8v*)&Pls[(mw * 16 + l15) * 584 + k0 + q * 8];
    short8v bb = *(const short8v*)(Vb + (long)(nw * 16 + l15) * 584 + k0 + q * 8);
    acc = __builtin_amdgcn_mfma_f32_16x16x32_bf16(a, bb, acc, 0, 0, 0);
  }
  int d = nw * 16 + l15;
  float vd = vdif_s[d];
#pragma unroll
  for (int reg = 0; reg < 4; ++reg) {
    int r = mw * 16 + q * 4 + reg;
    float o = acc[reg] * invd_s[r] + emv_s[r] * vd;
    int n = idx[bh * KTOP + row0 + r];
    ofull[((long)(b * N_PIX + n)) * 256 + h * 32 + d] = f2b(o);
  }
}

// ============ depthwise 3x3 (NHWC fp32 in -> NHWC bf16 out) ===========
__global__ __launch_bounds__(256) void dwconv_kernel(
    const float* __restrict__ xnhwc, const float* __restrict__ w,
    const float* __restrict__ bias, u16* __restrict__ out_nhwc)
{
  int pix = blockIdx.x;
  int b = pix / N_PIX; int p = pix - b * N_PIX;
  int y = p / 48, xx = p - y * 48;
  int c = threadIdx.x;
  float acc = bias[c];
#pragma unroll
  for (int ky = 0; ky < 3; ++ky) {
    int yy = y + ky - 1; if (yy < 0 || yy >= 48) continue;
#pragma unroll
    for (int kx = 0; kx < 3; ++kx) {
      int xc = xx + kx - 1; if (xc < 0 || xc >= 48) continue;
      acc += w[c * 9 + ky * 3 + kx] * xnhwc[((long)(b * N_PIX + yy * 48 + xc)) * 256 + c];
    }
  }
  out_nhwc[(long)pix * 256 + c] = f2b(acc);
}

// ============ spatial gate 7x7 (32ch -> 1), 256 threads ===============
__global__ __launch_bounds__(256) void sg2_kernel(
    const float* __restrict__ sga, const float* __restrict__ w,
    const float* __restrict__ b1, float* __restrict__ sgate)
{
  __shared__ float ws[32 * 49];
  __shared__ float red[4 * 64];
  int by = blockIdx.x; int b = by / 48, y = by - b * 48;
  int t = threadIdx.x;
  for (int i = t; i < 32 * 49; i += 256) ws[i] = w[i];
  __syncthreads();
  int xx = t & 63, gg = t >> 6;
  float acc = 0.f;
  if (xx < 48) {
    for (int ky = 0; ky < 7; ++ky) {
      int yy = y + ky - 3; if (yy < 0 || yy >= 48) continue;
      for (int kx = 0; kx < 7; ++kx) {
        int xc = xx + kx - 3; if (xc < 0 || xc >= 48) continue;
        const float4* sp = (const float4*)(sga + ((long)(b * N_PIX + yy * 48 + xc)) * 32 + gg * 8);
        float4 v0 = sp[0], v1 = sp[1];
        int wb = gg * 8 * 49 + ky * 7 + kx;
        acc += ws[wb] * v0.x + ws[wb + 49] * v0.y + ws[wb + 98] * v0.z + ws[wb + 147] * v0.w;
        acc += ws[wb + 196] * v1.x + ws[wb + 245] * v1.y + ws[wb + 294] * v1.z + ws[wb + 343] * v1.w;
      }
    }
  }
  red[gg * 64 + xx] = acc;
  __syncthreads();
  if (t < 48) {
    float tot = b1[0] + red[t] + red[64 + t] + red[128 + t] + red[192 + t];
    sgate[b * N_PIX + y * 48 + t] = 1.f / (1.f + expf(-tot));
  }
}

// ============ channel gate MLP (mean accumulated by pw epilogue) ======
__global__ __launch_bounds__(256) void cgmlp_kernel(
    const float* __restrict__ cgm, const float* __restrict__ w1, const float* __restrict__ b1,
    const float* __restrict__ w2, const float* __restrict__ b2, float* __restrict__ cgate)
{
  int b = blockIdx.x; int t = threadIdx.x;
  __shared__ float m[256];
  __shared__ float a[32];
  m[t] = cgm[b * 256 + t] * (1.f / (float)N_PIX);
  __syncthreads();
  if (t < 32) {
    float s = b1[t];
    for (int c = 0; c < 256; ++c) s += w1[t * 256 + c] * m[c];
    a[t] = s / (1.f + expf(-s));
  }
  __syncthreads();
  float s = b2[t];
#pragma unroll
  for (int g = 0; g < 32; ++g) s += w2[t * 32 + g] * a[g];
  cgate[b * 256 + t] = 1.f / (1.f + expf(-s));
}

// ============ fused x2 = x + gamma1*(xs*sg*cg)  +  LayerNorm2 =========
__global__ __launch_bounds__(256) void x2ln_kernel(
    const float* __restrict__ xnhwc, const u16* __restrict__ xs_bf,
    const float* __restrict__ sgate, const float* __restrict__ cgate,
    const float* __restrict__ gamma1, float* __restrict__ x2,
    const float* __restrict__ g, const float* __restrict__ bvec, u16* __restrict__ normed)
{
  __shared__ float red[256];
  int pix = blockIdx.x; int b = pix / N_PIX;
  int c = threadIdx.x;
  float xsv = b2f(xs_bf[(long)pix * 256 + c]);
  float v = xnhwc[(long)pix * 256 + c] + gamma1[0] * xsv * sgate[pix] * cgate[b * 256 + c];
  x2[(long)pix * 256 + c] = v;
  red[c] = v; __syncthreads();
  for (int off = 128; off > 0; off >>= 1) { if (c < off) red[c] += red[c + off]; __syncthreads(); }
  float mu = red[0] * (1.f / 256.f);
  __syncthreads();
  float dv = v - mu;
  red[c] = dv * dv; __syncthreads();
  for (int off = 128; off > 0; off >>= 1) { if (c < off) red[c] += red[c + off]; __syncthreads(); }
  float var = red[0] * (1.f / 256.f);
  normed[(long)pix * 256 + c] = f2b(dv * rsqrtf(var + 1e-6f) * g[c] + bvec[c]);
}

// ======================================================================
extern "C" void kernel_launch(void* const* d_in, const int* in_sizes, int n_in,
                              void* d_out, int out_size, void* d_ws, size_t ws_size,
                              hipStream_t stream) {
  (void)in_sizes; (void)n_in; (void)out_size; (void)ws_size;
  const float* x      = (const float*)d_in[0];
  const float* qkv_w  = (const float*)d_in[1];
  const float* out_w  = (const float*)d_in[2];
  const float* ln1_g  = (const float*)d_in[3];
  const float* ln1_b  = (const float*)d_in[4];
  const float* ln2_g  = (const float*)d_in[5];
  const float* ln2_b  = (const float*)d_in[6];
  const float* dw_w   = (const float*)d_in[7];
  const float* dw_b   = (const float*)d_in[8];
  const float* pw_w   = (const float*)d_in[9];
  const float* pw_b   = (const float*)d_in[10];
  const float* sg1_w  = (const float*)d_in[11];
  const float* sg1_b  = (const float*)d_in[12];
  const float* sg2_w  = (const float*)d_in[13];
  const float* sg2_b  = (const float*)d_in[14];
  const float* cg1_w  = (const float*)d_in[15];
  const float* cg1_b  = (const float*)d_in[16];
  const float* cg2_w  = (const float*)d_in[17];
  const float* cg2_b  = (const float*)d_in[18];
  const float* ff_w1  = (const float*)d_in[19];
  const float* ff_b1  = (const float*)d_in[20];
  const float* ff_w2  = (const float*)d_in[21];
  const float* ff_b2  = (const float*)d_in[22];
  const float* gamma1 = (const float*)d_in[23];
  const float* gamma2 = (const float*)d_in[24];
  float* out = (float*)d_out;
  float* ws  = (float*)d_ws;

  // -------- workspace layout (float units), total 9,899,520 fl = 39.6 MB ---
  float* qkv     = ws + 0;                  // 3,538,944 fp32; aliased h_bf / normed_bf
  float* attn_out= ws + 3538944;            // 1,179,648
  float* x2      = ws + 4718592;            // 1,179,648
  float* xnhwc   = ws + 5898240;            // 1,179,648
  u16*   ofull_bf= (u16*)(ws + 7077888);    // 589,824 fl
  u16*   xa_bf   = (u16*)(ws + 7667712);    // 589,824 fl ; later dwc_bf
  u16*   xs_bf   = (u16*)(ws + 8257536);    // 589,824 fl
  u16*   Qg_bf   = (u16*)(ws + 8847360);    // 147,456 fl
  u16*   Kg_bf   = (u16*)(ws + 8994816);    // 147,456 fl
  u16*   VgT     = (u16*)(ws + 9142272);    // 149,504 fl  [16][32][584]
  float* sga     = ws + 9291776;            // 147,456
  float* csum    = ws + 9439232;            // 1,536  [2][768]
  float* vneg    = ws + 9440768;            // 512
  float* cgm     = ws + 9441280;            // 512
  float* sgate   = ws + 9441792;            // 4,608
  float* cgate   = ws + 9446400;            // 512
  int*   idxb    = (int*)(ws + 9446912);    // 18,432 ints
  u16*   qkvBT   = (u16*)(ws + 9465344);    // 98,304 fl
  u16*   outBT   = (u16*)(ws + 9563648);    // 32,768 fl
  u16*   pwBT    = (u16*)(ws + 9596416);    // 32,768 fl
  u16*   ff1BT   = (u16*)(ws + 9629184);    // 131,072 fl
  u16*   ff2BT   = (u16*)(ws + 9760256);    // 131,072 fl
  u16*   sg1BT   = (u16*)(ws + 9891328);    // 8,192 fl -> end 9,899,520
  // aliases of qkv region (qkv fp32 dead after gather):
  u16*   h_bf     = (u16*)qkv;              // [0, 2,359,296) fl
  u16*   normed_bf= (u16*)(ws + 2359296);   // [2,359,296, 2,949,120) fl
  u16*   dwc_bf   = xa_bf;

  dim3 blk(256);
  hipMemsetAsync(csum, 0, 2560 * sizeof(float), stream);   // csum+vneg+cgm

  cast_all_kernel<<<dim3(3392), blk, 0, stream>>>(qkv_w, out_w, pw_w, ff_w1, ff_w2, sg1_w,
      qkvBT, outBT, pwBT, ff1BT, ff2BT, sg1BT);

  // ---- attention branch ----
  ln1t_kernel<<<dim3(144), blk, 0, stream>>>(x, xa_bf, xnhwc, ln1_g, ln1_b);
  mgemm<2, 0, 1><<<dim3(12, 36), blk, 0, stream>>>(xa_bf, qkvBT, qkv, nullptr,
      256, 768, 768, nullptr, nullptr, nullptr, csum, 768);
  topkscore_kernel<<<dim3(BHN, 2), blk, 0, stream>>>(qkv, csum, idxb);
  gather_kernel<<<dim3(72, BHN), blk, 0, stream>>>(qkv, idxb, Qg_bf, Kg_bf, VgT, vneg);
  ofill_kernel<<<dim3(NROWS), blk, 0, stream>>>(csum, ofull_bf);
  attn_kernel<<<dim3(18, BHN), blk, 0, stream>>>(Qg_bf, Kg_bf, VgT, csum, vneg, idxb, ofull_bf);
  mgemm<1, 0, 0><<<dim3(4, 72), blk, 0, stream>>>(ofull_bf, outBT, attn_out, nullptr,
      256, 256, 256, nullptr, nullptr, nullptr, nullptr, 0);

  // ---- conv branch ----
  dwconv_kernel<<<dim3(NROWS), blk, 0, stream>>>(xnhwc, dw_w, dw_b, dwc_bf);
  mgemm<1, 6, 1><<<dim3(4, 72), blk, 0, stream>>>(dwc_bf, pwBT, nullptr, xs_bf,
      256, 256, 256, pw_b, attn_out, nullptr, cgm, 256);

  // ---- gates ----
  mgemm<1, 3, 0><<<dim3(1, 72), blk, 0, stream>>>(xs_bf, sg1BT, sga, nullptr,
      256, 32, 32, sg1_b, nullptr, nullptr, nullptr, 0);
  sg2_kernel<<<dim3(96), blk, 0, stream>>>(sga, sg2_w, sg2_b, sgate);
  cgmlp_kernel<<<dim3(2), blk, 0, stream>>>(cgm, cg1_w, cg1_b, cg2_w, cg2_b, cgate);

  // ---- x2 + LN2 fused ----
  x2ln_kernel<<<dim3(NROWS), blk, 0, stream>>>(xnhwc, xs_bf, sgate, cgate, gamma1, x2,
      ln2_g, ln2_b, normed_bf);

  // ---- FFN ----
  mgemm<2, 4, 0><<<dim3(16, 36), blk, 0, stream>>>(normed_bf, ff1BT, nullptr, h_bf,
      256, 1024, 1024, ff_b1, nullptr, nullptr, nullptr, 0);
  mgemm<1, 5, 0><<<dim3(4, 72), blk, 0, stream>>>(h_bf, ff2BT, out, nullptr,
      1024, 256, 256, ff_b2, x2, gamma2, nullptr, 0);
}